// Round 10
// baseline (1527.968 us; speedup 1.0000x reference)
//
#include <hip/hip_runtime.h>

#define G 64
#define N 2048
#define E 32768
#define GN (G*N)   // 131072

typedef __attribute__((ext_vector_type(8))) short bf16x8;
typedef __attribute__((ext_vector_type(4))) float f32x4;

__device__ __forceinline__ float4 ld4(const float* p) { return *reinterpret_cast<const float4*>(p); }
__device__ __forceinline__ unsigned short f2bf(float x) {   // RNE
    unsigned u = __float_as_uint(x);
    u += 0x7FFF + ((u >> 16) & 1);
    return (unsigned short)(u >> 16);
}
__device__ __forceinline__ unsigned pack2(float a, float b) {
    return (unsigned)f2bf(a) | ((unsigned)f2bf(b) << 16);
}
__device__ __forceinline__ float bflo(unsigned u) { return __uint_as_float(u << 16); }
__device__ __forceinline__ float bfhi(unsigned u) { return __uint_as_float(u & 0xFFFF0000u); }
__device__ __forceinline__ float bfs(short s) { return __uint_as_float(((unsigned)(unsigned short)s) << 16); }

// bijective XCD swizzle (grid % 8 == 0): XCD x = bid&7 gets contiguous chunk
__device__ __forceinline__ int swz(int bid, int chunk) { return (bid & 7) * chunk + (bid >> 3); }

// ---------------- init: 0..63 CSR count+scan (offs/dinv); 64..103 weight prep; 104 tgt zero ----------------
__global__ __launch_bounds__(1024) void k_init(const int* __restrict__ ei,
        int* __restrict__ offs, float* __restrict__ dinv,
        const float* __restrict__ wres, const float* __restrict__ gw,
        const float* __restrict__ wfc, unsigned short* __restrict__ Wt,
        float* __restrict__ tgt) {
    int t = threadIdx.x;
    if (blockIdx.x == G + 40) {
        #pragma unroll
        for (int j = 0; j < 8; ++j) tgt[j*1024 + t] = 0.f;
        return;
    }
    if (blockIdx.x >= G) {
        if (t >= 256) return;
        int pb = blockIdx.x - G;           // 0..39
        int m = pb >> 3;
        int tid = (pb & 7) * 256 + t;      // 0..2047
        const float* src = (m == 0) ? wres : (m < 4 ? gw + (size_t)(m-1)*16384 : wfc);
        int c = tid >> 4, q = tid & 15;
        float v[8];
        #pragma unroll
        for (int j = 0; j < 8; ++j) v[j] = src[(q*8 + j)*128 + c];
        uint4 p;
        p.x = pack2(v[0], v[1]); p.y = pack2(v[2], v[3]);
        p.z = pack2(v[4], v[5]); p.w = pack2(v[6], v[7]);
        *reinterpret_cast<uint4*>(Wt + (size_t)m*16384 + c*128 + ((q ^ (c & 7)) << 3)) = p;
        return;
    }
    // ---- CSR count + scan ----
    int g = blockIdx.x;
    __shared__ int scnt[2048];
    __shared__ int swave[16];
    scnt[t] = 0; scnt[t + 1024] = 0;
    __syncthreads();
    const int* dstp = ei + (size_t)g*2*E + E;
    for (int e = t; e < E; e += 1024) atomicAdd(&scnt[dstp[e]], 1);
    __syncthreads();
    int a = scnt[2*t], b = scnt[2*t + 1];
    int s = a + b;
    int lane = t & 63, wid = t >> 6;
    #pragma unroll
    for (int d = 1; d < 64; d <<= 1) { int v = __shfl_up(s, d); if (lane >= d) s += v; }
    if (lane == 63) swave[wid] = s;
    __syncthreads();
    if (t < 16) {
        int v = swave[t];
        #pragma unroll
        for (int d = 1; d < 16; d <<= 1) { int u = __shfl_up(v, d); if (t >= d) v += u; }
        swave[t] = v;
    }
    __syncthreads();
    int woff = (wid == 0) ? 0 : swave[wid - 1];
    int e0 = woff + s - (a + b);
    int e1 = e0 + a;
    offs[g*(N+1) + 2*t]     = e0;
    offs[g*(N+1) + 2*t + 1] = e1;
    if (t == 0) offs[g*(N+1) + N] = E;
    dinv[(g<<11) + 2*t]     = rsqrtf((float)(a + 1));
    dinv[(g<<11) + 2*t + 1] = rsqrtf((float)(b + 1));
}

// ---------------- twin gather-GEMM (blocks G..G+511) + CSR fill (blocks 0..63) ----------------
// 512 thr, 256-row tiles
// X1 = relu(X0 @ W0 + bres);  Hb = (X0 @ W1) * dinv[row]
__global__ __launch_bounds__(512) void k_gemm_g2(const int* __restrict__ fidx,
        const float* __restrict__ tab, const unsigned short* __restrict__ Wt,
        const float* __restrict__ bres, const float* __restrict__ dinv,
        unsigned short* __restrict__ X1, unsigned short* __restrict__ Hb,
        const int* __restrict__ ei, const int* __restrict__ offs, int* __restrict__ adj) {
    __shared__ unsigned short sW[2*16384];   // 64 KB: W0 | W1 (fill blocks alias as cursor)
    const int t = threadIdx.x;

    if (blockIdx.x < G) {
        int* cur = reinterpret_cast<int*>(sW);
        int g = blockIdx.x;
        #pragma unroll
        for (int i = 0; i < 4; ++i) cur[i*512 + t] = offs[g*(N+1) + i*512 + t];
        __syncthreads();
        const int* srcp = ei + (size_t)g*2*E;
        const int* dstp = srcp + E;
        for (int e = t; e < E; e += 512) {
            int dst = dstp[e];
            int pos = atomicAdd(&cur[dst], 1);
            adj[(size_t)g*E + pos] = srcp[e];
        }
        return;
    }

    {
        const float4* s = reinterpret_cast<const float4*>(Wt);
        float4* d = reinterpret_cast<float4*>(sW);
        #pragma unroll
        for (int i = 0; i < 8; ++i) d[i*512 + t] = s[i*512 + t];
    }
    __syncthreads();

    const int lane = t & 63, w = t >> 6;
    const int wrow = (w & 3) << 6;     // 0,64,128,192
    const int wcol = (w >> 2) << 6;    // 0,64
    const size_t row0 = (size_t)swz(blockIdx.x - G, GN/256/8) * 256;
    const int l15 = lane & 15, l4 = lane >> 4;

    size_t rbase[4];
    const float* rowp[4];
    #pragma unroll
    for (int f2 = 0; f2 < 4; ++f2) {
        rbase[f2] = row0 + wrow + f2*16 + l15;
        rowp[f2] = tab + (size_t)fidx[rbase[f2]] * 128;
    }

    f32x4 acc0[4][4], acc1[4][4];
    #pragma unroll
    for (int i = 0; i < 4; ++i)
        #pragma unroll
        for (int j = 0; j < 4; ++j) {
            acc0[i][j] = (f32x4){0.f, 0.f, 0.f, 0.f};
            acc1[i][j] = (f32x4){0.f, 0.f, 0.f, 0.f};
        }

    #pragma unroll
    for (int kk = 0; kk < 4; ++kk) {
        bf16x8 xf[4];
        #pragma unroll
        for (int f2 = 0; f2 < 4; ++f2) {
            int col = (kk << 5) + (l4 << 3);
            float4 u = ld4(rowp[f2] + col);
            float4 v = ld4(rowp[f2] + col + 4);
            bf16x8 r;
            r[0] = (short)f2bf(u.x); r[1] = (short)f2bf(u.y);
            r[2] = (short)f2bf(u.z); r[3] = (short)f2bf(u.w);
            r[4] = (short)f2bf(v.x); r[5] = (short)f2bf(v.y);
            r[6] = (short)f2bf(v.z); r[7] = (short)f2bf(v.w);
            xf[f2] = r;
        }
        #pragma unroll
        for (int f = 0; f < 4; ++f) {
            int c = wcol + f*16 + l15;
            int off = c*128 + (((kk*4 + l4) ^ (c & 7)) << 3);
            bf16x8 wf0 = *reinterpret_cast<const bf16x8*>(&sW[off]);
            bf16x8 wf1 = *reinterpret_cast<const bf16x8*>(&sW[16384 + off]);
            #pragma unroll
            for (int f2 = 0; f2 < 4; ++f2) {
                acc0[f2][f] = __builtin_amdgcn_mfma_f32_16x16x32_bf16(wf0, xf[f2], acc0[f2][f], 0, 0, 0);
                acc1[f2][f] = __builtin_amdgcn_mfma_f32_16x16x32_bf16(wf1, xf[f2], acc1[f2][f], 0, 0, 0);
            }
        }
    }

    float dv[4];
    #pragma unroll
    for (int f2 = 0; f2 < 4; ++f2) dv[f2] = dinv[rbase[f2]];

    #pragma unroll
    for (int f = 0; f < 4; ++f) {
        int colb = wcol + f*16 + (l4 << 2);
        float4 bs = ld4(bres + colb);
        #pragma unroll
        for (int f2 = 0; f2 < 4; ++f2) {
            f32x4 v0 = acc0[f2][f];
            uint2 p0;
            p0.x = pack2(fmaxf(v0[0] + bs.x, 0.f), fmaxf(v0[1] + bs.y, 0.f));
            p0.y = pack2(fmaxf(v0[2] + bs.z, 0.f), fmaxf(v0[3] + bs.w, 0.f));
            *reinterpret_cast<uint2*>(X1 + (rbase[f2] << 7) + colb) = p0;
            f32x4 v1 = acc1[f2][f];
            float d = dv[f2];
            uint2 p1;
            p1.x = pack2(v1[0]*d, v1[1]*d);
            p1.y = pack2(v1[2]*d, v1[3]*d);
            *reinterpret_cast<uint2*>(Hb + (rbase[f2] << 7) + colb) = p1;
        }
    }
}

// ---------------- MFMA GEMM: 512 thr, 256-row tiles, XCD-swizzled ----------------
// MODE 1: C = (A@W) * dinv[row]
// MODE 2: colsum(relu((A+A2)@W + bias)) -> atomicAdd tgt  (no C write)
template<int MODE>
__global__ __launch_bounds__(512) void k_gemm(const unsigned short* __restrict__ A,
        const unsigned short* __restrict__ A2, const unsigned short* __restrict__ Wt,
        const float* __restrict__ bias, const float* __restrict__ dinv,
        unsigned short* __restrict__ C, float* __restrict__ tgt) {
    __shared__ unsigned short sW[16384];   // 32 KB, pre-swizzled
    const int t = threadIdx.x;
    {
        const float4* s = reinterpret_cast<const float4*>(Wt);
        float4* d = reinterpret_cast<float4*>(sW);
        #pragma unroll
        for (int i = 0; i < 4; ++i) d[i*512 + t] = s[i*512 + t];
    }
    __syncthreads();

    const int lane = t & 63, w = t >> 6;
    const int wrow = (w & 3) << 6;     // 0,64,128,192
    const int wcol = (w >> 2) << 6;    // 0,64
    const size_t row0 = (size_t)swz(blockIdx.x, GN/256/8) * 256;
    const int l15 = lane & 15, l4 = lane >> 4;

    size_t rbase[4];
    #pragma unroll
    for (int f2 = 0; f2 < 4; ++f2) rbase[f2] = row0 + wrow + f2*16 + l15;

    f32x4 acc[4][4];
    #pragma unroll
    for (int i = 0; i < 4; ++i)
        #pragma unroll
        for (int j = 0; j < 4; ++j) acc[i][j] = (f32x4){0.f, 0.f, 0.f, 0.f};

    #pragma unroll
    for (int kk = 0; kk < 4; ++kk) {
        bf16x8 xf[4];
        #pragma unroll
        for (int f2 = 0; f2 < 4; ++f2) {
            const unsigned short* ap = A + (rbase[f2] << 7) + (kk << 5) + (l4 << 3);
            if (MODE == 2) {
                bf16x8 x = *reinterpret_cast<const bf16x8*>(ap);
                bf16x8 y = *reinterpret_cast<const bf16x8*>(A2 + (rbase[f2] << 7) + (kk << 5) + (l4 << 3));
                bf16x8 r;
                #pragma unroll
                for (int j = 0; j < 8; ++j) r[j] = (short)f2bf(bfs(x[j]) + bfs(y[j]));
                xf[f2] = r;
            } else {
                xf[f2] = *reinterpret_cast<const bf16x8*>(ap);
            }
        }
        #pragma unroll
        for (int f = 0; f < 4; ++f) {
            int c = wcol + f*16 + l15;
            int off = c*128 + (((kk*4 + l4) ^ (c & 7)) << 3);
            bf16x8 wf = *reinterpret_cast<const bf16x8*>(&sW[off]);
            #pragma unroll
            for (int f2 = 0; f2 < 4; ++f2)
                acc[f2][f] = __builtin_amdgcn_mfma_f32_16x16x32_bf16(wf, xf[f2], acc[f2][f], 0, 0, 0);
        }
    }

    if (MODE == 2) {
        float cs[4][4];
        #pragma unroll
        for (int f = 0; f < 4; ++f) {
            int colb = wcol + f*16 + (l4 << 2);
            float4 bs = ld4(bias + colb);
            #pragma unroll
            for (int j = 0; j < 4; ++j) cs[f][j] = 0.f;
            #pragma unroll
            for (int f2 = 0; f2 < 4; ++f2) {
                cs[f][0] += fmaxf(acc[f2][f][0] + bs.x, 0.f);
                cs[f][1] += fmaxf(acc[f2][f][1] + bs.y, 0.f);
                cs[f][2] += fmaxf(acc[f2][f][2] + bs.z, 0.f);
                cs[f][3] += fmaxf(acc[f2][f][3] + bs.w, 0.f);
            }
        }
        #pragma unroll
        for (int d = 1; d < 16; d <<= 1)
            #pragma unroll
            for (int f = 0; f < 4; ++f)
                #pragma unroll
                for (int j = 0; j < 4; ++j)
                    cs[f][j] += __shfl_xor(cs[f][j], d);
        if (l15 == 0) {
            int g = (int)(row0 >> 11);
            #pragma unroll
            for (int f = 0; f < 4; ++f)
                #pragma unroll
                for (int j = 0; j < 4; ++j)
                    atomicAdd(&tgt[g*128 + wcol + f*16 + (l4 << 2) + j], cs[f][j]);
        }
        return;
    }

    float dv[4];
    #pragma unroll
    for (int f2 = 0; f2 < 4; ++f2) dv[f2] = dinv[rbase[f2]];
    #pragma unroll
    for (int f = 0; f < 4; ++f) {
        int colb = wcol + f*16 + (l4 << 2);
        #pragma unroll
        for (int f2 = 0; f2 < 4; ++f2) {
            f32x4 v = acc[f2][f];
            float d = dv[f2];
            uint2 p; p.x = pack2(v[0]*d, v[1]*d); p.y = pack2(v[2]*d, v[3]*d);
            *reinterpret_cast<uint2*>(C + (rbase[f2] << 7) + colb) = p;
        }
    }
}

// ---------------- aggregation: 16 edges in flight per wave ----------------
__global__ __launch_bounds__(256) void k_agg(const unsigned short* __restrict__ h,
        const int* __restrict__ adj, const int* __restrict__ offs,
        const float* __restrict__ dinv, const float* __restrict__ bias,
        unsigned short* __restrict__ out) {
    int bid = swz(blockIdx.x, GN/4/8);
    int wid = bid * 4 + (threadIdx.x >> 6);   // one wave per node
    int lane = threadIdx.x & 63;
    int g = wid >> 11, n = wid & (N-1);
    const unsigned short* hg = h + ((size_t)(g << 11) << 7);
    int st = offs[g*(N+1) + n];
    int en = offs[g*(N+1) + n + 1];
    const int* al = adj + (size_t)g*E;
    const int half = lane >> 5;        // 0: even edges, 1: odd edges
    const int c4 = (lane & 31) << 2;   // 4 cols per lane

    uint2 us = *reinterpret_cast<const uint2*>(hg + ((size_t)n << 7) + c4);
    float a0, a1, a2, a3;
    if (half == 0) {
        a0 = bflo(us.x); a1 = bfhi(us.x); a2 = bflo(us.y); a3 = bfhi(us.y);
    } else {
        a0 = 0.f; a1 = 0.f; a2 = 0.f; a3 = 0.f;
    }

    int e = st;
    for (; e + 16 <= en; e += 16) {
        int i0 = al[e + half],      i1 = al[e + 2 + half];
        int i2 = al[e + 4 + half],  i3 = al[e + 6 + half];
        int i4 = al[e + 8 + half],  i5 = al[e + 10 + half];
        int i6 = al[e + 12 + half], i7 = al[e + 14 + half];
        uint2 u0 = *reinterpret_cast<const uint2*>(hg + ((size_t)i0 << 7) + c4);
        uint2 u1 = *reinterpret_cast<const uint2*>(hg + ((size_t)i1 << 7) + c4);
        uint2 u2 = *reinterpret_cast<const uint2*>(hg + ((size_t)i2 << 7) + c4);
        uint2 u3 = *reinterpret_cast<const uint2*>(hg + ((size_t)i3 << 7) + c4);
        uint2 u4 = *reinterpret_cast<const uint2*>(hg + ((size_t)i4 << 7) + c4);
        uint2 u5 = *reinterpret_cast<const uint2*>(hg + ((size_t)i5 << 7) + c4);
        uint2 u6 = *reinterpret_cast<const uint2*>(hg + ((size_t)i6 << 7) + c4);
        uint2 u7 = *reinterpret_cast<const uint2*>(hg + ((size_t)i7 << 7) + c4);
        a0 += ((bflo(u0.x) + bflo(u1.x)) + (bflo(u2.x) + bflo(u3.x)))
            + ((bflo(u4.x) + bflo(u5.x)) + (bflo(u6.x) + bflo(u7.x)));
        a1 += ((bfhi(u0.x) + bfhi(u1.x)) + (bfhi(u2.x) + bfhi(u3.x)))
            + ((bfhi(u4.x) + bfhi(u5.x)) + (bfhi(u6.x) + bfhi(u7.x)));
        a2 += ((bflo(u0.y) + bflo(u1.y)) + (bflo(u2.y) + bflo(u3.y)))
            + ((bflo(u4.y) + bflo(u5.y)) + (bflo(u6.y) + bflo(u7.y)));
        a3 += ((bfhi(u0.y) + bfhi(u1.y)) + (bfhi(u2.y) + bfhi(u3.y)))
            + ((bfhi(u4.y) + bfhi(u5.y)) + (bfhi(u6.y) + bfhi(u7.y)));
    }
    for (; e + 4 <= en; e += 4) {
        int i0 = al[e + half];
        int i1 = al[e + 2 + half];
        uint2 u0 = *reinterpret_cast<const uint2*>(hg + ((size_t)i0 << 7) + c4);
        uint2 u1 = *reinterpret_cast<const uint2*>(hg + ((size_t)i1 << 7) + c4);
        a0 += bflo(u0.x) + bflo(u1.x);
        a1 += bfhi(u0.x) + bfhi(u1.x);
        a2 += bflo(u0.y) + bflo(u1.y);
        a3 += bfhi(u0.y) + bfhi(u1.y);
    }
    if (e + 2 <= en) {
        int i = al[e + half];
        uint2 u = *reinterpret_cast<const uint2*>(hg + ((size_t)i << 7) + c4);
        a0 += bflo(u.x); a1 += bfhi(u.x); a2 += bflo(u.y); a3 += bfhi(u.y);
        e += 2;
    }
    if (e < en) {
        int i = al[e];
        uint2 u = *reinterpret_cast<const uint2*>(hg + ((size_t)i << 7) + c4);
        if (half == 0) {
            a0 += bflo(u.x); a1 += bfhi(u.x); a2 += bflo(u.y); a3 += bfhi(u.y);
        }
    }

    a0 += __shfl_xor(a0, 32); a1 += __shfl_xor(a1, 32);
    a2 += __shfl_xor(a2, 32); a3 += __shfl_xor(a3, 32);

    if (half == 0) {
        float d = dinv[wid];
        float4 bs = ld4(bias + c4);
        uint2 pv;
        pv.x = pack2(fmaxf(a0*d + bs.x, 0.f), fmaxf(a1*d + bs.y, 0.f));
        pv.y = pack2(fmaxf(a2*d + bs.z, 0.f), fmaxf(a3*d + bs.w, 0.f));
        *reinterpret_cast<uint2*>(out + ((size_t)wid << 7) + c4) = pv;
    }
}

// ---------------- logits + log_softmax: one wave per graph ----------------
__global__ __launch_bounds__(64) void k_final(const float* __restrict__ tgt,
        const float* __restrict__ lw, const float* __restrict__ lb, float* __restrict__ outp) {
    int g = blockIdx.x, lane = threadIdx.x;
    float l0 = 0.f, l1 = 0.f;
    #pragma unroll
    for (int c = lane; c < 128; c += 64) {
        float v = tgt[g*128 + c] * (1.0f/2048.0f);
        l0 += v * lw[c*2];
        l1 += v * lw[c*2 + 1];
    }
    #pragma unroll
    for (int d = 32; d; d >>= 1) { l0 += __shfl_xor(l0, d); l1 += __shfl_xor(l1, d); }
    if (lane == 0) {
        l0 += lb[0]; l1 += lb[1];
        float m = fmaxf(l0, l1);
        float lse = m + logf(expf(l0 - m) + expf(l1 - m));
        outp[g*2]         = l0 - lse;
        outp[g*2 + 1]     = l1 - lse;
        outp[G*2 + g*2]     = l0;
        outp[G*2 + g*2 + 1] = l1;
    }
}

extern "C" void kernel_launch(void* const* d_in, const int* in_sizes, int n_in,
                              void* d_out, int out_size, void* d_ws, size_t ws_size,
                              hipStream_t stream) {
    const float* all_features = (const float*)d_in[0];
    const int*   fidx = (const int*)d_in[1];
    const int*   ei   = (const int*)d_in[2];
    // d_in[3] = action (always 2 -> 3 GCN layers)
    const float* wres = (const float*)d_in[4];
    const float* bres = (const float*)d_in[5];
    const float* gw   = (const float*)d_in[6];
    const float* gb   = (const float*)d_in[7];
    const float* wfc  = (const float*)d_in[8];
    const float* bfc  = (const float*)d_in[9];
    const float* lw   = (const float*)d_in[10];
    const float* lb   = (const float*)d_in[11];
    float* out = (float*)d_out;

    char* ws = (char*)d_ws;
    size_t o = 0;
    auto alloc = [&](size_t bytes) { char* p = ws + o; o += (bytes + 255) & ~(size_t)255; return p; };
    unsigned short* X  = (unsigned short*)alloc((size_t)GN*128*2);   // agg output
    unsigned short* Hb = (unsigned short*)alloc((size_t)GN*128*2);   // h'
    unsigned short* X1 = (unsigned short*)alloc((size_t)GN*128*2);   // residual
    unsigned short* scratch = (unsigned short*)alloc((size_t)GN*128*2); // ablation sink
    unsigned short* Wt = (unsigned short*)alloc((size_t)5*16384*2);
    int*   adj  = (int*)alloc((size_t)G*E*4);
    int*   offs = (int*)alloc((size_t)G*(N+1)*4);
    float* dinv = (float*)alloc((size_t)GN*4);
    float* tgt  = (float*)alloc((size_t)G*128*4);

    // CSR count/scan + weight prep + tgt zero (one launch)
    k_init<<<G + 41, 1024, 0, stream>>>(ei, offs, dinv, wres, gw, wfc, Wt, tgt);

    // twin gather-GEMM (blocks 64..575) with CSR fill overlapped (blocks 0..63)
    k_gemm_g2<<<G + GN/256, 512, 0, stream>>>(fidx, all_features, Wt, bres, dinv, X1, Hb,
                                              ei, offs, adj);

    // layer 0 aggregation, then layers 1..2
    k_agg<<<GN/4, 256, 0, stream>>>(Hb, adj, offs, dinv, gb, X);
    for (int l = 1; l < 3; ++l) {
        k_gemm<1><<<GN/256, 512, 0, stream>>>(X, nullptr, Wt + (size_t)(1+l)*16384, nullptr, dinv, Hb, nullptr);
        k_agg<<<GN/4, 256, 0, stream>>>(Hb, adj, offs, dinv, gb + (size_t)l*128, X);
    }

    // fc1 + mean fused: atomicAdd col-sums of relu((X+X1)@Wfc+bfc) into tgt
    k_gemm<2><<<GN/256, 512, 0, stream>>>(X, X1, Wt + (size_t)4*16384, bfc, nullptr, nullptr, tgt);

    k_final<<<G, 64, 0, stream>>>(tgt, lw, lb, out);

    // ---------- ABLATION (R10): 16 extra identical aggs into scratch ----------
    // dur_us delta vs R8 (368.8) / 16 = marginal cost of one k_agg dispatch.
    // Deterministic; does not touch d_out.
    for (int r = 0; r < 16; ++r)
        k_agg<<<GN/4, 256, 0, stream>>>(Hb, adj, offs, dinv, gb, scratch);
}

// Round 11
// 311.913 us; speedup vs baseline: 4.8987x; 4.8987x over previous
//
#include <hip/hip_runtime.h>

#define G 64
#define N 2048
#define E 32768
#define GN (G*N)   // 131072
#define PADR 36    // shorts per LDS row (72 B, 8B-aligned, bank-floor for random b64)

typedef __attribute__((ext_vector_type(8))) short bf16x8;
typedef __attribute__((ext_vector_type(4))) float f32x4;

__device__ __forceinline__ float4 ld4(const float* p) { return *reinterpret_cast<const float4*>(p); }
__device__ __forceinline__ unsigned short f2bf(float x) {   // RNE
    unsigned u = __float_as_uint(x);
    u += 0x7FFF + ((u >> 16) & 1);
    return (unsigned short)(u >> 16);
}
__device__ __forceinline__ unsigned pack2(float a, float b) {
    return (unsigned)f2bf(a) | ((unsigned)f2bf(b) << 16);
}
__device__ __forceinline__ float bflo(unsigned u) { return __uint_as_float(u << 16); }
__device__ __forceinline__ float bfhi(unsigned u) { return __uint_as_float(u & 0xFFFF0000u); }
__device__ __forceinline__ float bfs(short s) { return __uint_as_float(((unsigned)(unsigned short)s) << 16); }

// bijective XCD swizzle (grid % 8 == 0)
__device__ __forceinline__ int swz(int bid, int chunk) { return (bid & 7) * chunk + (bid >> 3); }

// ---------------- init: 0..63 CSR count+scan (offs/dinv); 64..103 weight prep; 104 tgt zero ----------------
__global__ __launch_bounds__(1024) void k_init(const int* __restrict__ ei,
        int* __restrict__ offs, float* __restrict__ dinv,
        const float* __restrict__ wres, const float* __restrict__ gw,
        const float* __restrict__ wfc, unsigned short* __restrict__ Wt,
        float* __restrict__ tgt) {
    int t = threadIdx.x;
    if (blockIdx.x == G + 40) {
        #pragma unroll
        for (int j = 0; j < 8; ++j) tgt[j*1024 + t] = 0.f;
        return;
    }
    if (blockIdx.x >= G) {
        if (t >= 256) return;
        int pb = blockIdx.x - G;           // 0..39
        int m = pb >> 3;
        int tid = (pb & 7) * 256 + t;      // 0..2047
        const float* src = (m == 0) ? wres : (m < 4 ? gw + (size_t)(m-1)*16384 : wfc);
        int c = tid >> 4, q = tid & 15;
        float v[8];
        #pragma unroll
        for (int j = 0; j < 8; ++j) v[j] = src[(q*8 + j)*128 + c];
        uint4 p;
        p.x = pack2(v[0], v[1]); p.y = pack2(v[2], v[3]);
        p.z = pack2(v[4], v[5]); p.w = pack2(v[6], v[7]);
        *reinterpret_cast<uint4*>(Wt + (size_t)m*16384 + c*128 + ((q ^ (c & 7)) << 3)) = p;
        return;
    }
    // ---- CSR count + scan ----
    int g = blockIdx.x;
    __shared__ int scnt[2048];
    __shared__ int swave[16];
    scnt[t] = 0; scnt[t + 1024] = 0;
    __syncthreads();
    const int* dstp = ei + (size_t)g*2*E + E;
    for (int e = t; e < E; e += 1024) atomicAdd(&scnt[dstp[e]], 1);
    __syncthreads();
    int a = scnt[2*t], b = scnt[2*t + 1];
    int s = a + b;
    int lane = t & 63, wid = t >> 6;
    #pragma unroll
    for (int d = 1; d < 64; d <<= 1) { int v = __shfl_up(s, d); if (lane >= d) s += v; }
    if (lane == 63) swave[wid] = s;
    __syncthreads();
    if (t < 16) {
        int v = swave[t];
        #pragma unroll
        for (int d = 1; d < 16; d <<= 1) { int u = __shfl_up(v, d); if (t >= d) v += u; }
        swave[t] = v;
    }
    __syncthreads();
    int woff = (wid == 0) ? 0 : swave[wid - 1];
    int e0 = woff + s - (a + b);
    int e1 = e0 + a;
    offs[g*(N+1) + 2*t]     = e0;
    offs[g*(N+1) + 2*t + 1] = e1;
    if (t == 0) offs[g*(N+1) + N] = E;
    dinv[(g<<11) + 2*t]     = rsqrtf((float)(a + 1));
    dinv[(g<<11) + 2*t + 1] = rsqrtf((float)(b + 1));
}

// ---------------- twin gather-GEMM (blocks G..G+511) + CSR fill (blocks 0..63) ----------------
// 512 thr, 256-row tiles
// X1 = relu(X0 @ W0 + bres);  Hb = (X0 @ W1) * dinv[row]
__global__ __launch_bounds__(512) void k_gemm_g2(const int* __restrict__ fidx,
        const float* __restrict__ tab, const unsigned short* __restrict__ Wt,
        const float* __restrict__ bres, const float* __restrict__ dinv,
        unsigned short* __restrict__ X1, unsigned short* __restrict__ Hb,
        const int* __restrict__ ei, const int* __restrict__ offs, int* __restrict__ adj) {
    __shared__ unsigned short sW[2*16384];   // 64 KB: W0 | W1 (fill blocks alias as cursor)
    const int t = threadIdx.x;

    if (blockIdx.x < G) {
        int* cur = reinterpret_cast<int*>(sW);
        int g = blockIdx.x;
        #pragma unroll
        for (int i = 0; i < 4; ++i) cur[i*512 + t] = offs[g*(N+1) + i*512 + t];
        __syncthreads();
        const int* srcp = ei + (size_t)g*2*E;
        const int* dstp = srcp + E;
        for (int e = t; e < E; e += 512) {
            int dst = dstp[e];
            int pos = atomicAdd(&cur[dst], 1);
            adj[(size_t)g*E + pos] = srcp[e];
        }
        return;
    }

    {
        const float4* s = reinterpret_cast<const float4*>(Wt);
        float4* d = reinterpret_cast<float4*>(sW);
        #pragma unroll
        for (int i = 0; i < 8; ++i) d[i*512 + t] = s[i*512 + t];
    }
    __syncthreads();

    const int lane = t & 63, w = t >> 6;
    const int wrow = (w & 3) << 6;     // 0,64,128,192
    const int wcol = (w >> 2) << 6;    // 0,64
    const size_t row0 = (size_t)swz(blockIdx.x - G, GN/256/8) * 256;
    const int l15 = lane & 15, l4 = lane >> 4;

    size_t rbase[4];
    const float* rowp[4];
    #pragma unroll
    for (int f2 = 0; f2 < 4; ++f2) {
        rbase[f2] = row0 + wrow + f2*16 + l15;
        rowp[f2] = tab + (size_t)fidx[rbase[f2]] * 128;
    }

    f32x4 acc0[4][4], acc1[4][4];
    #pragma unroll
    for (int i = 0; i < 4; ++i)
        #pragma unroll
        for (int j = 0; j < 4; ++j) {
            acc0[i][j] = (f32x4){0.f, 0.f, 0.f, 0.f};
            acc1[i][j] = (f32x4){0.f, 0.f, 0.f, 0.f};
        }

    #pragma unroll
    for (int kk = 0; kk < 4; ++kk) {
        bf16x8 xf[4];
        #pragma unroll
        for (int f2 = 0; f2 < 4; ++f2) {
            int col = (kk << 5) + (l4 << 3);
            float4 u = ld4(rowp[f2] + col);
            float4 v = ld4(rowp[f2] + col + 4);
            bf16x8 r;
            r[0] = (short)f2bf(u.x); r[1] = (short)f2bf(u.y);
            r[2] = (short)f2bf(u.z); r[3] = (short)f2bf(u.w);
            r[4] = (short)f2bf(v.x); r[5] = (short)f2bf(v.y);
            r[6] = (short)f2bf(v.z); r[7] = (short)f2bf(v.w);
            xf[f2] = r;
        }
        #pragma unroll
        for (int f = 0; f < 4; ++f) {
            int c = wcol + f*16 + l15;
            int off = c*128 + (((kk*4 + l4) ^ (c & 7)) << 3);
            bf16x8 wf0 = *reinterpret_cast<const bf16x8*>(&sW[off]);
            bf16x8 wf1 = *reinterpret_cast<const bf16x8*>(&sW[16384 + off]);
            #pragma unroll
            for (int f2 = 0; f2 < 4; ++f2) {
                acc0[f2][f] = __builtin_amdgcn_mfma_f32_16x16x32_bf16(wf0, xf[f2], acc0[f2][f], 0, 0, 0);
                acc1[f2][f] = __builtin_amdgcn_mfma_f32_16x16x32_bf16(wf1, xf[f2], acc1[f2][f], 0, 0, 0);
            }
        }
    }

    float dv[4];
    #pragma unroll
    for (int f2 = 0; f2 < 4; ++f2) dv[f2] = dinv[rbase[f2]];

    #pragma unroll
    for (int f = 0; f < 4; ++f) {
        int colb = wcol + f*16 + (l4 << 2);
        float4 bs = ld4(bres + colb);
        #pragma unroll
        for (int f2 = 0; f2 < 4; ++f2) {
            f32x4 v0 = acc0[f2][f];
            uint2 p0;
            p0.x = pack2(fmaxf(v0[0] + bs.x, 0.f), fmaxf(v0[1] + bs.y, 0.f));
            p0.y = pack2(fmaxf(v0[2] + bs.z, 0.f), fmaxf(v0[3] + bs.w, 0.f));
            *reinterpret_cast<uint2*>(X1 + (rbase[f2] << 7) + colb) = p0;
            f32x4 v1 = acc1[f2][f];
            float d = dv[f2];
            uint2 p1;
            p1.x = pack2(v1[0]*d, v1[1]*d);
            p1.y = pack2(v1[2]*d, v1[3]*d);
            *reinterpret_cast<uint2*>(Hb + (rbase[f2] << 7) + colb) = p1;
        }
    }
}

// ---------------- MFMA GEMM: 512 thr, 256-row tiles, XCD-swizzled ----------------
// MODE 1: C = (A@W) * dinv[row]
// MODE 2: colsum(relu((A+A2)@W + bias)) -> atomicAdd tgt  (no C write)
template<int MODE>
__global__ __launch_bounds__(512) void k_gemm(const unsigned short* __restrict__ A,
        const unsigned short* __restrict__ A2, const unsigned short* __restrict__ Wt,
        const float* __restrict__ bias, const float* __restrict__ dinv,
        unsigned short* __restrict__ C, float* __restrict__ tgt) {
    __shared__ unsigned short sW[16384];   // 32 KB, pre-swizzled
    const int t = threadIdx.x;
    {
        const float4* s = reinterpret_cast<const float4*>(Wt);
        float4* d = reinterpret_cast<float4*>(sW);
        #pragma unroll
        for (int i = 0; i < 4; ++i) d[i*512 + t] = s[i*512 + t];
    }
    __syncthreads();

    const int lane = t & 63, w = t >> 6;
    const int wrow = (w & 3) << 6;     // 0,64,128,192
    const int wcol = (w >> 2) << 6;    // 0,64
    const size_t row0 = (size_t)swz(blockIdx.x, GN/256/8) * 256;
    const int l15 = lane & 15, l4 = lane >> 4;

    size_t rbase[4];
    #pragma unroll
    for (int f2 = 0; f2 < 4; ++f2) rbase[f2] = row0 + wrow + f2*16 + l15;

    f32x4 acc[4][4];
    #pragma unroll
    for (int i = 0; i < 4; ++i)
        #pragma unroll
        for (int j = 0; j < 4; ++j) acc[i][j] = (f32x4){0.f, 0.f, 0.f, 0.f};

    #pragma unroll
    for (int kk = 0; kk < 4; ++kk) {
        bf16x8 xf[4];
        #pragma unroll
        for (int f2 = 0; f2 < 4; ++f2) {
            const unsigned short* ap = A + (rbase[f2] << 7) + (kk << 5) + (l4 << 3);
            if (MODE == 2) {
                bf16x8 x = *reinterpret_cast<const bf16x8*>(ap);
                bf16x8 y = *reinterpret_cast<const bf16x8*>(A2 + (rbase[f2] << 7) + (kk << 5) + (l4 << 3));
                bf16x8 r;
                #pragma unroll
                for (int j = 0; j < 8; ++j) r[j] = (short)f2bf(bfs(x[j]) + bfs(y[j]));
                xf[f2] = r;
            } else {
                xf[f2] = *reinterpret_cast<const bf16x8*>(ap);
            }
        }
        #pragma unroll
        for (int f = 0; f < 4; ++f) {
            int c = wcol + f*16 + l15;
            int off = c*128 + (((kk*4 + l4) ^ (c & 7)) << 3);
            bf16x8 wf = *reinterpret_cast<const bf16x8*>(&sW[off]);
            #pragma unroll
            for (int f2 = 0; f2 < 4; ++f2)
                acc[f2][f] = __builtin_amdgcn_mfma_f32_16x16x32_bf16(wf, xf[f2], acc[f2][f], 0, 0, 0);
        }
    }

    if (MODE == 2) {
        float cs[4][4];
        #pragma unroll
        for (int f = 0; f < 4; ++f) {
            int colb = wcol + f*16 + (l4 << 2);
            float4 bs = ld4(bias + colb);
            #pragma unroll
            for (int j = 0; j < 4; ++j) cs[f][j] = 0.f;
            #pragma unroll
            for (int f2 = 0; f2 < 4; ++f2) {
                cs[f][0] += fmaxf(acc[f2][f][0] + bs.x, 0.f);
                cs[f][1] += fmaxf(acc[f2][f][1] + bs.y, 0.f);
                cs[f][2] += fmaxf(acc[f2][f][2] + bs.z, 0.f);
                cs[f][3] += fmaxf(acc[f2][f][3] + bs.w, 0.f);
            }
        }
        #pragma unroll
        for (int d = 1; d < 16; d <<= 1)
            #pragma unroll
            for (int f = 0; f < 4; ++f)
                #pragma unroll
                for (int j = 0; j < 4; ++j)
                    cs[f][j] += __shfl_xor(cs[f][j], d);
        if (l15 == 0) {
            int g = (int)(row0 >> 11);
            #pragma unroll
            for (int f = 0; f < 4; ++f)
                #pragma unroll
                for (int j = 0; j < 4; ++j)
                    atomicAdd(&tgt[g*128 + wcol + f*16 + (l4 << 2) + j], cs[f][j]);
        }
        return;
    }

    float dv[4];
    #pragma unroll
    for (int f2 = 0; f2 < 4; ++f2) dv[f2] = dinv[rbase[f2]];
    #pragma unroll
    for (int f = 0; f < 4; ++f) {
        int colb = wcol + f*16 + (l4 << 2);
        #pragma unroll
        for (int f2 = 0; f2 < 4; ++f2) {
            f32x4 v = acc[f2][f];
            float d = dv[f2];
            uint2 p; p.x = pack2(v[0]*d, v[1]*d); p.y = pack2(v[2]*d, v[3]*d);
            *reinterpret_cast<uint2*>(C + (rbase[f2] << 7) + colb) = p;
        }
    }
}

// ---------------- aggregation via LDS slice: block = (graph, 32-col slice) ----------------
// Stage h'[g][:, c0:c0+32] (2048 rows x 64 B, padded to 72 B) into LDS once; each thread
// pulls 4 nodes' in-edges from LDS with 32 fp32 register accumulators.
__global__ __launch_bounds__(512) void k_agg(const unsigned short* __restrict__ h,
        const int* __restrict__ adj, const int* __restrict__ offs,
        const float* __restrict__ dinv, const float* __restrict__ bias,
        unsigned short* __restrict__ out) {
    __shared__ unsigned short sIN[2048 * PADR];   // 144 KB
    const int t = threadIdx.x;
    const int g  = blockIdx.x >> 2;
    const int c0 = (blockIdx.x & 3) << 5;         // 0,32,64,96
    const unsigned short* hg = h + (((size_t)g << 11) << 7) + c0;

    // stage: 8 lanes per row, 8 B each (coalesced 64B-line reads; bank-floor LDS writes)
    {
        int r0 = t >> 3;     // 0..63
        int j  = t & 7;      // 8B chunk
        for (int i = 0; i < 32; ++i) {
            int r = r0 + (i << 6);
            uint2 v = *reinterpret_cast<const uint2*>(hg + ((size_t)r << 7) + j*4);
            *reinterpret_cast<uint2*>(&sIN[r*PADR + j*4]) = v;
        }
    }
    __syncthreads();

    const int* al = adj + (size_t)g*E;
    // hoist bias slice (32 fp32)
    float bs[32];
    #pragma unroll
    for (int q = 0; q < 8; ++q) {
        float4 b4 = ld4(bias + c0 + q*4);
        bs[q*4] = b4.x; bs[q*4+1] = b4.y; bs[q*4+2] = b4.z; bs[q*4+3] = b4.w;
    }

    for (int i = 0; i < 4; ++i) {
        int n = t + (i << 9);
        int st = offs[g*(N+1) + n];
        int en = offs[g*(N+1) + n + 1];
        float acc[32];
        {   // self-loop init from LDS
            const unsigned short* rp = &sIN[n*PADR];
            #pragma unroll
            for (int q = 0; q < 8; ++q) {
                uint2 u = *reinterpret_cast<const uint2*>(rp + q*4);
                acc[q*4]   = bflo(u.x); acc[q*4+1] = bfhi(u.x);
                acc[q*4+2] = bflo(u.y); acc[q*4+3] = bfhi(u.y);
            }
        }
        for (int e = st; e < en; ++e) {
            int s = al[e];
            const unsigned short* rp = &sIN[s*PADR];
            #pragma unroll
            for (int q = 0; q < 8; ++q) {
                uint2 u = *reinterpret_cast<const uint2*>(rp + q*4);
                acc[q*4]   += bflo(u.x); acc[q*4+1] += bfhi(u.x);
                acc[q*4+2] += bflo(u.y); acc[q*4+3] += bfhi(u.y);
            }
        }
        float d = dinv[(g << 11) + n];
        uint4 o0, o1;
        o0.x = pack2(fmaxf(acc[0]*d+bs[0],0.f),  fmaxf(acc[1]*d+bs[1],0.f));
        o0.y = pack2(fmaxf(acc[2]*d+bs[2],0.f),  fmaxf(acc[3]*d+bs[3],0.f));
        o0.z = pack2(fmaxf(acc[4]*d+bs[4],0.f),  fmaxf(acc[5]*d+bs[5],0.f));
        o0.w = pack2(fmaxf(acc[6]*d+bs[6],0.f),  fmaxf(acc[7]*d+bs[7],0.f));
        o1.x = pack2(fmaxf(acc[8]*d+bs[8],0.f),  fmaxf(acc[9]*d+bs[9],0.f));
        o1.y = pack2(fmaxf(acc[10]*d+bs[10],0.f),fmaxf(acc[11]*d+bs[11],0.f));
        o1.z = pack2(fmaxf(acc[12]*d+bs[12],0.f),fmaxf(acc[13]*d+bs[13],0.f));
        o1.w = pack2(fmaxf(acc[14]*d+bs[14],0.f),fmaxf(acc[15]*d+bs[15],0.f));
        unsigned short* op = out + (((size_t)(g << 11) + n) << 7) + c0;
        *reinterpret_cast<uint4*>(op) = o0;
        *reinterpret_cast<uint4*>(op + 8) = o1;
        uint4 o2, o3;
        o2.x = pack2(fmaxf(acc[16]*d+bs[16],0.f),fmaxf(acc[17]*d+bs[17],0.f));
        o2.y = pack2(fmaxf(acc[18]*d+bs[18],0.f),fmaxf(acc[19]*d+bs[19],0.f));
        o2.z = pack2(fmaxf(acc[20]*d+bs[20],0.f),fmaxf(acc[21]*d+bs[21],0.f));
        o2.w = pack2(fmaxf(acc[22]*d+bs[22],0.f),fmaxf(acc[23]*d+bs[23],0.f));
        o3.x = pack2(fmaxf(acc[24]*d+bs[24],0.f),fmaxf(acc[25]*d+bs[25],0.f));
        o3.y = pack2(fmaxf(acc[26]*d+bs[26],0.f),fmaxf(acc[27]*d+bs[27],0.f));
        o3.z = pack2(fmaxf(acc[28]*d+bs[28],0.f),fmaxf(acc[29]*d+bs[29],0.f));
        o3.w = pack2(fmaxf(acc[30]*d+bs[30],0.f),fmaxf(acc[31]*d+bs[31],0.f));
        *reinterpret_cast<uint4*>(op + 16) = o2;
        *reinterpret_cast<uint4*>(op + 24) = o3;
    }
}

// ---------------- logits + log_softmax: one wave per graph ----------------
__global__ __launch_bounds__(64) void k_final(const float* __restrict__ tgt,
        const float* __restrict__ lw, const float* __restrict__ lb, float* __restrict__ outp) {
    int g = blockIdx.x, lane = threadIdx.x;
    float l0 = 0.f, l1 = 0.f;
    #pragma unroll
    for (int c = lane; c < 128; c += 64) {
        float v = tgt[g*128 + c] * (1.0f/2048.0f);
        l0 += v * lw[c*2];
        l1 += v * lw[c*2 + 1];
    }
    #pragma unroll
    for (int d = 32; d; d >>= 1) { l0 += __shfl_xor(l0, d); l1 += __shfl_xor(l1, d); }
    if (lane == 0) {
        l0 += lb[0]; l1 += lb[1];
        float m = fmaxf(l0, l1);
        float lse = m + logf(expf(l0 - m) + expf(l1 - m));
        outp[g*2]         = l0 - lse;
        outp[g*2 + 1]     = l1 - lse;
        outp[G*2 + g*2]     = l0;
        outp[G*2 + g*2 + 1] = l1;
    }
}

extern "C" void kernel_launch(void* const* d_in, const int* in_sizes, int n_in,
                              void* d_out, int out_size, void* d_ws, size_t ws_size,
                              hipStream_t stream) {
    const float* all_features = (const float*)d_in[0];
    const int*   fidx = (const int*)d_in[1];
    const int*   ei   = (const int*)d_in[2];
    // d_in[3] = action (always 2 -> 3 GCN layers)
    const float* wres = (const float*)d_in[4];
    const float* bres = (const float*)d_in[5];
    const float* gw   = (const float*)d_in[6];
    const float* gb   = (const float*)d_in[7];
    const float* wfc  = (const float*)d_in[8];
    const float* bfc  = (const float*)d_in[9];
    const float* lw   = (const float*)d_in[10];
    const float* lb   = (const float*)d_in[11];
    float* out = (float*)d_out;

    char* ws = (char*)d_ws;
    size_t o = 0;
    auto alloc = [&](size_t bytes) { char* p = ws + o; o += (bytes + 255) & ~(size_t)255; return p; };
    unsigned short* X  = (unsigned short*)alloc((size_t)GN*128*2);   // agg output
    unsigned short* Hb = (unsigned short*)alloc((size_t)GN*128*2);   // h'
    unsigned short* X1 = (unsigned short*)alloc((size_t)GN*128*2);   // residual
    unsigned short* Wt = (unsigned short*)alloc((size_t)5*16384*2);
    int*   adj  = (int*)alloc((size_t)G*E*4);
    int*   offs = (int*)alloc((size_t)G*(N+1)*4);
    float* dinv = (float*)alloc((size_t)GN*4);
    float* tgt  = (float*)alloc((size_t)G*128*4);

    // CSR count/scan + weight prep + tgt zero (one launch)
    k_init<<<G + 41, 1024, 0, stream>>>(ei, offs, dinv, wres, gw, wfc, Wt, tgt);

    // twin gather-GEMM (blocks 64..575) with CSR fill overlapped (blocks 0..63)
    k_gemm_g2<<<G + GN/256, 512, 0, stream>>>(fidx, all_features, Wt, bres, dinv, X1, Hb,
                                              ei, offs, adj);

    // layer 0 aggregation, then layers 1..2
    k_agg<<<G*4, 512, 0, stream>>>(Hb, adj, offs, dinv, gb, X);
    for (int l = 1; l < 3; ++l) {
        k_gemm<1><<<GN/256, 512, 0, stream>>>(X, nullptr, Wt + (size_t)(1+l)*16384, nullptr, dinv, Hb, nullptr);
        k_agg<<<G*4, 512, 0, stream>>>(Hb, adj, offs, dinv, gb + (size_t)l*128, X);
    }

    // fc1 + mean fused: atomicAdd col-sums of relu((X+X1)@Wfc+bfc) into tgt
    k_gemm<2><<<GN/256, 512, 0, stream>>>(X, X1, Wt + (size_t)4*16384, bfc, nullptr, nullptr, tgt);

    k_final<<<G, 64, 0, stream>>>(tgt, lw, lb, out);
}

// Round 12
// 292.248 us; speedup vs baseline: 5.2283x; 1.0673x over previous
//
#include <hip/hip_runtime.h>

#define G 64
#define N 2048
#define E 32768
#define GN (G*N)   // 131072
#define PADR 36    // shorts per LDS row (72 B)

typedef __attribute__((ext_vector_type(8))) short bf16x8;
typedef __attribute__((ext_vector_type(4))) float f32x4;

__device__ __forceinline__ float4 ld4(const float* p) { return *reinterpret_cast<const float4*>(p); }
__device__ __forceinline__ unsigned short f2bf(float x) {   // RNE
    unsigned u = __float_as_uint(x);
    u += 0x7FFF + ((u >> 16) & 1);
    return (unsigned short)(u >> 16);
}
__device__ __forceinline__ unsigned pack2(float a, float b) {
    return (unsigned)f2bf(a) | ((unsigned)f2bf(b) << 16);
}
__device__ __forceinline__ float bflo(unsigned u) { return __uint_as_float(u << 16); }
__device__ __forceinline__ float bfhi(unsigned u) { return __uint_as_float(u & 0xFFFF0000u); }
__device__ __forceinline__ float bfs(short s) { return __uint_as_float(((unsigned)(unsigned short)s) << 16); }

// bijective XCD swizzle (grid % 8 == 0)
__device__ __forceinline__ int swz(int bid, int chunk) { return (bid & 7) * chunk + (bid >> 3); }

// ---------------- init: 0..63 CSR count+scan (offs/dinv); 64..103 weight prep; 104 tgt zero ----------------
__global__ __launch_bounds__(1024) void k_init(const int* __restrict__ ei,
        int* __restrict__ offs, float* __restrict__ dinv,
        const float* __restrict__ wres, const float* __restrict__ gw,
        const float* __restrict__ wfc, unsigned short* __restrict__ Wt,
        float* __restrict__ tgt) {
    int t = threadIdx.x;
    if (blockIdx.x == G + 40) {
        #pragma unroll
        for (int j = 0; j < 8; ++j) tgt[j*1024 + t] = 0.f;
        return;
    }
    if (blockIdx.x >= G) {
        if (t >= 256) return;
        int pb = blockIdx.x - G;           // 0..39
        int m = pb >> 3;
        int tid = (pb & 7) * 256 + t;      // 0..2047
        const float* src = (m == 0) ? wres : (m < 4 ? gw + (size_t)(m-1)*16384 : wfc);
        int c = tid >> 4, q = tid & 15;
        float v[8];
        #pragma unroll
        for (int j = 0; j < 8; ++j) v[j] = src[(q*8 + j)*128 + c];
        uint4 p;
        p.x = pack2(v[0], v[1]); p.y = pack2(v[2], v[3]);
        p.z = pack2(v[4], v[5]); p.w = pack2(v[6], v[7]);
        *reinterpret_cast<uint4*>(Wt + (size_t)m*16384 + c*128 + ((q ^ (c & 7)) << 3)) = p;
        return;
    }
    // ---- CSR count + scan ----
    int g = blockIdx.x;
    __shared__ int scnt[2048];
    __shared__ int swave[16];
    scnt[t] = 0; scnt[t + 1024] = 0;
    __syncthreads();
    const int* dstp = ei + (size_t)g*2*E + E;
    for (int e = t; e < E; e += 1024) atomicAdd(&scnt[dstp[e]], 1);
    __syncthreads();
    int a = scnt[2*t], b = scnt[2*t + 1];
    int s = a + b;
    int lane = t & 63, wid = t >> 6;
    #pragma unroll
    for (int d = 1; d < 64; d <<= 1) { int v = __shfl_up(s, d); if (lane >= d) s += v; }
    if (lane == 63) swave[wid] = s;
    __syncthreads();
    if (t < 16) {
        int v = swave[t];
        #pragma unroll
        for (int d = 1; d < 16; d <<= 1) { int u = __shfl_up(v, d); if (t >= d) v += u; }
        swave[t] = v;
    }
    __syncthreads();
    int woff = (wid == 0) ? 0 : swave[wid - 1];
    int e0 = woff + s - (a + b);
    int e1 = e0 + a;
    offs[g*(N+1) + 2*t]     = e0;
    offs[g*(N+1) + 2*t + 1] = e1;
    if (t == 0) offs[g*(N+1) + N] = E;
    dinv[(g<<11) + 2*t]     = rsqrtf((float)(a + 1));
    dinv[(g<<11) + 2*t + 1] = rsqrtf((float)(b + 1));
}

// ---------------- twin gather-GEMM (blocks G..G+511) + CSR fill (blocks 0..63) ----------------
// 512 thr, 256-row tiles
// X1 = relu(X0 @ W0 + bres);  Hb = (X0 @ W1) * dinv[row]
__global__ __launch_bounds__(512) void k_gemm_g2(const int* __restrict__ fidx,
        const float* __restrict__ tab, const unsigned short* __restrict__ Wt,
        const float* __restrict__ bres, const float* __restrict__ dinv,
        unsigned short* __restrict__ X1, unsigned short* __restrict__ Hb,
        const int* __restrict__ ei, const int* __restrict__ offs, int* __restrict__ adj) {
    __shared__ unsigned short sW[2*16384];   // 64 KB: W0 | W1 (fill blocks alias as cursor)
    const int t = threadIdx.x;

    if (blockIdx.x < G) {
        int* cur = reinterpret_cast<int*>(sW);
        int g = blockIdx.x;
        #pragma unroll
        for (int i = 0; i < 4; ++i) cur[i*512 + t] = offs[g*(N+1) + i*512 + t];
        __syncthreads();
        const int* srcp = ei + (size_t)g*2*E;
        const int* dstp = srcp + E;
        for (int e = t; e < E; e += 512) {
            int dst = dstp[e];
            int pos = atomicAdd(&cur[dst], 1);
            adj[(size_t)g*E + pos] = srcp[e];
        }
        return;
    }

    {
        const float4* s = reinterpret_cast<const float4*>(Wt);
        float4* d = reinterpret_cast<float4*>(sW);
        #pragma unroll
        for (int i = 0; i < 8; ++i) d[i*512 + t] = s[i*512 + t];
    }
    __syncthreads();

    const int lane = t & 63, w = t >> 6;
    const int wrow = (w & 3) << 6;     // 0,64,128,192
    const int wcol = (w >> 2) << 6;    // 0,64
    const size_t row0 = (size_t)swz(blockIdx.x - G, GN/256/8) * 256;
    const int l15 = lane & 15, l4 = lane >> 4;

    size_t rbase[4];
    const float* rowp[4];
    #pragma unroll
    for (int f2 = 0; f2 < 4; ++f2) {
        rbase[f2] = row0 + wrow + f2*16 + l15;
        rowp[f2] = tab + (size_t)fidx[rbase[f2]] * 128;
    }

    f32x4 acc0[4][4], acc1[4][4];
    #pragma unroll
    for (int i = 0; i < 4; ++i)
        #pragma unroll
        for (int j = 0; j < 4; ++j) {
            acc0[i][j] = (f32x4){0.f, 0.f, 0.f, 0.f};
            acc1[i][j] = (f32x4){0.f, 0.f, 0.f, 0.f};
        }

    #pragma unroll
    for (int kk = 0; kk < 4; ++kk) {
        bf16x8 xf[4];
        #pragma unroll
        for (int f2 = 0; f2 < 4; ++f2) {
            int col = (kk << 5) + (l4 << 3);
            float4 u = ld4(rowp[f2] + col);
            float4 v = ld4(rowp[f2] + col + 4);
            bf16x8 r;
            r[0] = (short)f2bf(u.x); r[1] = (short)f2bf(u.y);
            r[2] = (short)f2bf(u.z); r[3] = (short)f2bf(u.w);
            r[4] = (short)f2bf(v.x); r[5] = (short)f2bf(v.y);
            r[6] = (short)f2bf(v.z); r[7] = (short)f2bf(v.w);
            xf[f2] = r;
        }
        #pragma unroll
        for (int f = 0; f < 4; ++f) {
            int c = wcol + f*16 + l15;
            int off = c*128 + (((kk*4 + l4) ^ (c & 7)) << 3);
            bf16x8 wf0 = *reinterpret_cast<const bf16x8*>(&sW[off]);
            bf16x8 wf1 = *reinterpret_cast<const bf16x8*>(&sW[16384 + off]);
            #pragma unroll
            for (int f2 = 0; f2 < 4; ++f2) {
                acc0[f2][f] = __builtin_amdgcn_mfma_f32_16x16x32_bf16(wf0, xf[f2], acc0[f2][f], 0, 0, 0);
                acc1[f2][f] = __builtin_amdgcn_mfma_f32_16x16x32_bf16(wf1, xf[f2], acc1[f2][f], 0, 0, 0);
            }
        }
    }

    float dv[4];
    #pragma unroll
    for (int f2 = 0; f2 < 4; ++f2) dv[f2] = dinv[rbase[f2]];

    #pragma unroll
    for (int f = 0; f < 4; ++f) {
        int colb = wcol + f*16 + (l4 << 2);
        float4 bs = ld4(bres + colb);
        #pragma unroll
        for (int f2 = 0; f2 < 4; ++f2) {
            f32x4 v0 = acc0[f2][f];
            uint2 p0;
            p0.x = pack2(fmaxf(v0[0] + bs.x, 0.f), fmaxf(v0[1] + bs.y, 0.f));
            p0.y = pack2(fmaxf(v0[2] + bs.z, 0.f), fmaxf(v0[3] + bs.w, 0.f));
            *reinterpret_cast<uint2*>(X1 + (rbase[f2] << 7) + colb) = p0;
            f32x4 v1 = acc1[f2][f];
            float d = dv[f2];
            uint2 p1;
            p1.x = pack2(v1[0]*d, v1[1]*d);
            p1.y = pack2(v1[2]*d, v1[3]*d);
            *reinterpret_cast<uint2*>(Hb + (rbase[f2] << 7) + colb) = p1;
        }
    }
}

// ---------------- MFMA GEMM: 512 thr, 256-row tiles, XCD-swizzled ----------------
// MODE 1: C = (A@W) * dinv[row]
// MODE 2: colsum(relu((A+A2)@W + bias)) -> atomicAdd tgt  (no C write)
template<int MODE>
__global__ __launch_bounds__(512) void k_gemm(const unsigned short* __restrict__ A,
        const unsigned short* __restrict__ A2, const unsigned short* __restrict__ Wt,
        const float* __restrict__ bias, const float* __restrict__ dinv,
        unsigned short* __restrict__ C, float* __restrict__ tgt) {
    __shared__ unsigned short sW[16384];   // 32 KB, pre-swizzled
    const int t = threadIdx.x;
    {
        const float4* s = reinterpret_cast<const float4*>(Wt);
        float4* d = reinterpret_cast<float4*>(sW);
        #pragma unroll
        for (int i = 0; i < 4; ++i) d[i*512 + t] = s[i*512 + t];
    }
    __syncthreads();

    const int lane = t & 63, w = t >> 6;
    const int wrow = (w & 3) << 6;     // 0,64,128,192
    const int wcol = (w >> 2) << 6;    // 0,64
    const size_t row0 = (size_t)swz(blockIdx.x, GN/256/8) * 256;
    const int l15 = lane & 15, l4 = lane >> 4;

    size_t rbase[4];
    #pragma unroll
    for (int f2 = 0; f2 < 4; ++f2) rbase[f2] = row0 + wrow + f2*16 + l15;

    f32x4 acc[4][4];
    #pragma unroll
    for (int i = 0; i < 4; ++i)
        #pragma unroll
        for (int j = 0; j < 4; ++j) acc[i][j] = (f32x4){0.f, 0.f, 0.f, 0.f};

    #pragma unroll
    for (int kk = 0; kk < 4; ++kk) {
        bf16x8 xf[4];
        #pragma unroll
        for (int f2 = 0; f2 < 4; ++f2) {
            const unsigned short* ap = A + (rbase[f2] << 7) + (kk << 5) + (l4 << 3);
            if (MODE == 2) {
                bf16x8 x = *reinterpret_cast<const bf16x8*>(ap);
                bf16x8 y = *reinterpret_cast<const bf16x8*>(A2 + (rbase[f2] << 7) + (kk << 5) + (l4 << 3));
                bf16x8 r;
                #pragma unroll
                for (int j = 0; j < 8; ++j) r[j] = (short)f2bf(bfs(x[j]) + bfs(y[j]));
                xf[f2] = r;
            } else {
                xf[f2] = *reinterpret_cast<const bf16x8*>(ap);
            }
        }
        #pragma unroll
        for (int f = 0; f < 4; ++f) {
            int c = wcol + f*16 + l15;
            int off = c*128 + (((kk*4 + l4) ^ (c & 7)) << 3);
            bf16x8 wf = *reinterpret_cast<const bf16x8*>(&sW[off]);
            #pragma unroll
            for (int f2 = 0; f2 < 4; ++f2)
                acc[f2][f] = __builtin_amdgcn_mfma_f32_16x16x32_bf16(wf, xf[f2], acc[f2][f], 0, 0, 0);
        }
    }

    if (MODE == 2) {
        float cs[4][4];
        #pragma unroll
        for (int f = 0; f < 4; ++f) {
            int colb = wcol + f*16 + (l4 << 2);
            float4 bs = ld4(bias + colb);
            #pragma unroll
            for (int j = 0; j < 4; ++j) cs[f][j] = 0.f;
            #pragma unroll
            for (int f2 = 0; f2 < 4; ++f2) {
                cs[f][0] += fmaxf(acc[f2][f][0] + bs.x, 0.f);
                cs[f][1] += fmaxf(acc[f2][f][1] + bs.y, 0.f);
                cs[f][2] += fmaxf(acc[f2][f][2] + bs.z, 0.f);
                cs[f][3] += fmaxf(acc[f2][f][3] + bs.w, 0.f);
            }
        }
        #pragma unroll
        for (int d = 1; d < 16; d <<= 1)
            #pragma unroll
            for (int f = 0; f < 4; ++f)
                #pragma unroll
                for (int j = 0; j < 4; ++j)
                    cs[f][j] += __shfl_xor(cs[f][j], d);
        if (l15 == 0) {
            int g = (int)(row0 >> 11);
            #pragma unroll
            for (int f = 0; f < 4; ++f)
                #pragma unroll
                for (int j = 0; j < 4; ++j)
                    atomicAdd(&tgt[g*128 + wcol + f*16 + (l4 << 2) + j], cs[f][j]);
        }
        return;
    }

    float dv[4];
    #pragma unroll
    for (int f2 = 0; f2 < 4; ++f2) dv[f2] = dinv[rbase[f2]];
    #pragma unroll
    for (int f = 0; f < 4; ++f) {
        int colb = wcol + f*16 + (l4 << 2);
        #pragma unroll
        for (int f2 = 0; f2 < 4; ++f2) {
            f32x4 v = acc[f2][f];
            float d = dv[f2];
            uint2 p; p.x = pack2(v[0]*d, v[1]*d); p.y = pack2(v[2]*d, v[3]*d);
            *reinterpret_cast<uint2*>(C + (rbase[f2] << 7) + colb) = p;
        }
    }
}

// ---------------- aggregation via LDS slice: 1024 thr, 2 nodes/thread, edge loop x2 ----------------
__global__ __launch_bounds__(1024) void k_agg(const unsigned short* __restrict__ h,
        const int* __restrict__ adj, const int* __restrict__ offs,
        const float* __restrict__ dinv, const float* __restrict__ bias,
        unsigned short* __restrict__ out) {
    __shared__ unsigned short sIN[2048 * PADR];   // 144 KB
    const int t = threadIdx.x;
    const int g  = blockIdx.x >> 2;
    const int c0 = (blockIdx.x & 3) << 5;         // 0,32,64,96
    const unsigned short* hg = h + (((size_t)g << 11) << 7) + c0;

    // stage: 8 lanes per row, 8 B each
    {
        int r0 = t >> 3;     // 0..127
        int j  = t & 7;      // 8B chunk
        for (int i = 0; i < 16; ++i) {
            int r = r0 + (i << 7);
            uint2 v = *reinterpret_cast<const uint2*>(hg + ((size_t)r << 7) + j*4);
            *reinterpret_cast<uint2*>(&sIN[r*PADR + j*4]) = v;
        }
    }
    __syncthreads();

    const int* al = adj + (size_t)g*E;
    float bs[32];
    #pragma unroll
    for (int q = 0; q < 8; ++q) {
        float4 b4 = ld4(bias + c0 + q*4);
        bs[q*4] = b4.x; bs[q*4+1] = b4.y; bs[q*4+2] = b4.z; bs[q*4+3] = b4.w;
    }

    #pragma unroll
    for (int i = 0; i < 2; ++i) {
        int n = t + (i << 10);
        int st = offs[g*(N+1) + n];
        int en = offs[g*(N+1) + n + 1];
        float acc[32];
        {   // self-loop init from LDS
            const unsigned short* rp = &sIN[n*PADR];
            #pragma unroll
            for (int q = 0; q < 8; ++q) {
                uint2 u = *reinterpret_cast<const uint2*>(rp + q*4);
                acc[q*4]   = bflo(u.x); acc[q*4+1] = bfhi(u.x);
                acc[q*4+2] = bflo(u.y); acc[q*4+3] = bfhi(u.y);
            }
        }
        int e = st;
        for (; e + 2 <= en; e += 2) {   // 2 edges in flight: 16 independent LDS reads
            int s0 = al[e], s1 = al[e+1];
            const unsigned short* rp0 = &sIN[s0*PADR];
            const unsigned short* rp1 = &sIN[s1*PADR];
            uint2 u0[8], u1[8];
            #pragma unroll
            for (int q = 0; q < 8; ++q) u0[q] = *reinterpret_cast<const uint2*>(rp0 + q*4);
            #pragma unroll
            for (int q = 0; q < 8; ++q) u1[q] = *reinterpret_cast<const uint2*>(rp1 + q*4);
            #pragma unroll
            for (int q = 0; q < 8; ++q) {
                acc[q*4]   += bflo(u0[q].x) + bflo(u1[q].x);
                acc[q*4+1] += bfhi(u0[q].x) + bfhi(u1[q].x);
                acc[q*4+2] += bflo(u0[q].y) + bflo(u1[q].y);
                acc[q*4+3] += bfhi(u0[q].y) + bfhi(u1[q].y);
            }
        }
        if (e < en) {
            const unsigned short* rp = &sIN[al[e]*PADR];
            #pragma unroll
            for (int q = 0; q < 8; ++q) {
                uint2 u = *reinterpret_cast<const uint2*>(rp + q*4);
                acc[q*4]   += bflo(u.x); acc[q*4+1] += bfhi(u.x);
                acc[q*4+2] += bflo(u.y); acc[q*4+3] += bfhi(u.y);
            }
        }
        float d = dinv[(g << 11) + n];
        unsigned short* op = out + (((size_t)(g << 11) + n) << 7) + c0;
        uint4 o0, o1;
        o0.x = pack2(fmaxf(acc[0]*d+bs[0],0.f),  fmaxf(acc[1]*d+bs[1],0.f));
        o0.y = pack2(fmaxf(acc[2]*d+bs[2],0.f),  fmaxf(acc[3]*d+bs[3],0.f));
        o0.z = pack2(fmaxf(acc[4]*d+bs[4],0.f),  fmaxf(acc[5]*d+bs[5],0.f));
        o0.w = pack2(fmaxf(acc[6]*d+bs[6],0.f),  fmaxf(acc[7]*d+bs[7],0.f));
        o1.x = pack2(fmaxf(acc[8]*d+bs[8],0.f),  fmaxf(acc[9]*d+bs[9],0.f));
        o1.y = pack2(fmaxf(acc[10]*d+bs[10],0.f),fmaxf(acc[11]*d+bs[11],0.f));
        o1.z = pack2(fmaxf(acc[12]*d+bs[12],0.f),fmaxf(acc[13]*d+bs[13],0.f));
        o1.w = pack2(fmaxf(acc[14]*d+bs[14],0.f),fmaxf(acc[15]*d+bs[15],0.f));
        *reinterpret_cast<uint4*>(op) = o0;
        *reinterpret_cast<uint4*>(op + 8) = o1;
        uint4 o2, o3;
        o2.x = pack2(fmaxf(acc[16]*d+bs[16],0.f),fmaxf(acc[17]*d+bs[17],0.f));
        o2.y = pack2(fmaxf(acc[18]*d+bs[18],0.f),fmaxf(acc[19]*d+bs[19],0.f));
        o2.z = pack2(fmaxf(acc[20]*d+bs[20],0.f),fmaxf(acc[21]*d+bs[21],0.f));
        o2.w = pack2(fmaxf(acc[22]*d+bs[22],0.f),fmaxf(acc[23]*d+bs[23],0.f));
        o3.x = pack2(fmaxf(acc[24]*d+bs[24],0.f),fmaxf(acc[25]*d+bs[25],0.f));
        o3.y = pack2(fmaxf(acc[26]*d+bs[26],0.f),fmaxf(acc[27]*d+bs[27],0.f));
        o3.z = pack2(fmaxf(acc[28]*d+bs[28],0.f),fmaxf(acc[29]*d+bs[29],0.f));
        o3.w = pack2(fmaxf(acc[30]*d+bs[30],0.f),fmaxf(acc[31]*d+bs[31],0.f));
        *reinterpret_cast<uint4*>(op + 16) = o2;
        *reinterpret_cast<uint4*>(op + 24) = o3;
    }
}

// ---------------- logits + log_softmax: one wave per graph ----------------
__global__ __launch_bounds__(64) void k_final(const float* __restrict__ tgt,
        const float* __restrict__ lw, const float* __restrict__ lb, float* __restrict__ outp) {
    int g = blockIdx.x, lane = threadIdx.x;
    float l0 = 0.f, l1 = 0.f;
    #pragma unroll
    for (int c = lane; c < 128; c += 64) {
        float v = tgt[g*128 + c] * (1.0f/2048.0f);
        l0 += v * lw[c*2];
        l1 += v * lw[c*2 + 1];
    }
    #pragma unroll
    for (int d = 32; d; d >>= 1) { l0 += __shfl_xor(l0, d); l1 += __shfl_xor(l1, d); }
    if (lane == 0) {
        l0 += lb[0]; l1 += lb[1];
        float m = fmaxf(l0, l1);
        float lse = m + logf(expf(l0 - m) + expf(l1 - m));
        outp[g*2]         = l0 - lse;
        outp[g*2 + 1]     = l1 - lse;
        outp[G*2 + g*2]     = l0;
        outp[G*2 + g*2 + 1] = l1;
    }
}

extern "C" void kernel_launch(void* const* d_in, const int* in_sizes, int n_in,
                              void* d_out, int out_size, void* d_ws, size_t ws_size,
                              hipStream_t stream) {
    const float* all_features = (const float*)d_in[0];
    const int*   fidx = (const int*)d_in[1];
    const int*   ei   = (const int*)d_in[2];
    // d_in[3] = action (always 2 -> 3 GCN layers)
    const float* wres = (const float*)d_in[4];
    const float* bres = (const float*)d_in[5];
    const float* gw   = (const float*)d_in[6];
    const float* gb   = (const float*)d_in[7];
    const float* wfc  = (const float*)d_in[8];
    const float* bfc  = (const float*)d_in[9];
    const float* lw   = (const float*)d_in[10];
    const float* lb   = (const float*)d_in[11];
    float* out = (float*)d_out;

    char* ws = (char*)d_ws;
    size_t o = 0;
    auto alloc = [&](size_t bytes) { char* p = ws + o; o += (bytes + 255) & ~(size_t)255; return p; };
    unsigned short* X  = (unsigned short*)alloc((size_t)GN*128*2);   // agg output
    unsigned short* Hb = (unsigned short*)alloc((size_t)GN*128*2);   // h'
    unsigned short* X1 = (unsigned short*)alloc((size_t)GN*128*2);   // residual
    unsigned short* Wt = (unsigned short*)alloc((size_t)5*16384*2);
    int*   adj  = (int*)alloc((size_t)G*E*4);
    int*   offs = (int*)alloc((size_t)G*(N+1)*4);
    float* dinv = (float*)alloc((size_t)GN*4);
    float* tgt  = (float*)alloc((size_t)G*128*4);

    // CSR count/scan + weight prep + tgt zero (one launch)
    k_init<<<G + 41, 1024, 0, stream>>>(ei, offs, dinv, wres, gw, wfc, Wt, tgt);

    // twin gather-GEMM (blocks 64..575) with CSR fill overlapped (blocks 0..63)
    k_gemm_g2<<<G + GN/256, 512, 0, stream>>>(fidx, all_features, Wt, bres, dinv, X1, Hb,
                                              ei, offs, adj);

    // layer 0 aggregation, then layers 1..2
    k_agg<<<G*4, 1024, 0, stream>>>(Hb, adj, offs, dinv, gb, X);
    for (int l = 1; l < 3; ++l) {
        k_gemm<1><<<GN/256, 512, 0, stream>>>(X, nullptr, Wt + (size_t)(1+l)*16384, nullptr, dinv, Hb, nullptr);
        k_agg<<<G*4, 1024, 0, stream>>>(Hb, adj, offs, dinv, gb + (size_t)l*128, X);
    }

    // fc1 + mean fused: atomicAdd col-sums of relu((X+X1)@Wfc+bfc) into tgt
    k_gemm<2><<<GN/256, 512, 0, stream>>>(X, X1, Wt + (size_t)4*16384, bfc, nullptr, nullptr, tgt);

    k_final<<<G, 64, 0, stream>>>(tgt, lw, lb, out);
}

// Round 13
// 286.983 us; speedup vs baseline: 5.3242x; 1.0183x over previous
//
#include <hip/hip_runtime.h>

#define G 64
#define N 2048
#define E 32768
#define GN (G*N)   // 131072
#define PADR 40    // shorts per LDS row (80 B: 16B-aligned, bank-optimal for random b128)

typedef __attribute__((ext_vector_type(8))) short bf16x8;
typedef __attribute__((ext_vector_type(4))) float f32x4;

__device__ __forceinline__ float4 ld4(const float* p) { return *reinterpret_cast<const float4*>(p); }
__device__ __forceinline__ unsigned short f2bf(float x) {   // RNE
    unsigned u = __float_as_uint(x);
    u += 0x7FFF + ((u >> 16) & 1);
    return (unsigned short)(u >> 16);
}
__device__ __forceinline__ unsigned pack2(float a, float b) {
    return (unsigned)f2bf(a) | ((unsigned)f2bf(b) << 16);
}
__device__ __forceinline__ float bflo(unsigned u) { return __uint_as_float(u << 16); }
__device__ __forceinline__ float bfhi(unsigned u) { return __uint_as_float(u & 0xFFFF0000u); }
__device__ __forceinline__ float bfs(short s) { return __uint_as_float(((unsigned)(unsigned short)s) << 16); }

// bijective XCD swizzle (grid % 8 == 0)
__device__ __forceinline__ int swz(int bid, int chunk) { return (bid & 7) * chunk + (bid >> 3); }

// ---------------- init: 0..63 CSR count+scan+degree-sort; 64..103 weight prep; 104 tgt zero ----------------
__global__ __launch_bounds__(1024) void k_init(const int* __restrict__ ei,
        int* __restrict__ offs, float* __restrict__ dinv, int* __restrict__ perm,
        const float* __restrict__ wres, const float* __restrict__ gw,
        const float* __restrict__ wfc, unsigned short* __restrict__ Wt,
        float* __restrict__ tgt) {
    int t = threadIdx.x;
    if (blockIdx.x == G + 40) {
        #pragma unroll
        for (int j = 0; j < 8; ++j) tgt[j*1024 + t] = 0.f;
        return;
    }
    if (blockIdx.x >= G) {
        if (t >= 256) return;
        int pb = blockIdx.x - G;           // 0..39
        int m = pb >> 3;
        int tid = (pb & 7) * 256 + t;      // 0..2047
        const float* src = (m == 0) ? wres : (m < 4 ? gw + (size_t)(m-1)*16384 : wfc);
        int c = tid >> 4, q = tid & 15;
        float v[8];
        #pragma unroll
        for (int j = 0; j < 8; ++j) v[j] = src[(q*8 + j)*128 + c];
        uint4 p;
        p.x = pack2(v[0], v[1]); p.y = pack2(v[2], v[3]);
        p.z = pack2(v[4], v[5]); p.w = pack2(v[6], v[7]);
        *reinterpret_cast<uint4*>(Wt + (size_t)m*16384 + c*128 + ((q ^ (c & 7)) << 3)) = p;
        return;
    }
    // ---- CSR count + scan + degree counting-sort ----
    int g = blockIdx.x;
    __shared__ int scnt[2048];
    __shared__ int swave[16];
    __shared__ int hist[64];
    scnt[t] = 0; scnt[t + 1024] = 0;
    if (t < 64) hist[t] = 0;
    __syncthreads();
    const int* dstp = ei + (size_t)g*2*E + E;
    for (int e = t; e < E; e += 1024) atomicAdd(&scnt[dstp[e]], 1);
    __syncthreads();
    int a = scnt[2*t], b = scnt[2*t + 1];
    int s = a + b;
    int lane = t & 63, wid = t >> 6;
    #pragma unroll
    for (int d = 1; d < 64; d <<= 1) { int v = __shfl_up(s, d); if (lane >= d) s += v; }
    if (lane == 63) swave[wid] = s;
    __syncthreads();
    if (t < 16) {
        int v = swave[t];
        #pragma unroll
        for (int d = 1; d < 16; d <<= 1) { int u = __shfl_up(v, d); if (t >= d) v += u; }
        swave[t] = v;
    }
    __syncthreads();
    int woff = (wid == 0) ? 0 : swave[wid - 1];
    int e0 = woff + s - (a + b);
    int e1 = e0 + a;
    offs[g*(N+1) + 2*t]     = e0;
    offs[g*(N+1) + 2*t + 1] = e1;
    if (t == 0) offs[g*(N+1) + N] = E;
    dinv[(g<<11) + 2*t]     = rsqrtf((float)(a + 1));
    dinv[(g<<11) + 2*t + 1] = rsqrtf((float)(b + 1));
    // degree histogram
    int ba = min(a, 63), bb = min(b, 63);
    atomicAdd(&hist[ba], 1);
    atomicAdd(&hist[bb], 1);
    __syncthreads();
    if (t < 64) {   // exclusive prefix over 64 bins (one wave)
        int v = hist[t];
        int inc = v;
        #pragma unroll
        for (int d = 1; d < 64; d <<= 1) { int u = __shfl_up(inc, d); if (t >= d) inc += u; }
        hist[t] = inc - v;
    }
    __syncthreads();
    int sa = atomicAdd(&hist[ba], 1);
    perm[(g<<11) + sa] = 2*t;
    int sb = atomicAdd(&hist[bb], 1);
    perm[(g<<11) + sb] = 2*t + 1;
}

// ---------------- twin gather-GEMM (blocks G..G+511) + CSR fill (blocks 0..63) ----------------
// 512 thr, 256-row tiles
// X1 = relu(X0 @ W0 + bres);  Hb = (X0 @ W1) * dinv[row]
__global__ __launch_bounds__(512) void k_gemm_g2(const int* __restrict__ fidx,
        const float* __restrict__ tab, const unsigned short* __restrict__ Wt,
        const float* __restrict__ bres, const float* __restrict__ dinv,
        unsigned short* __restrict__ X1, unsigned short* __restrict__ Hb,
        const int* __restrict__ ei, const int* __restrict__ offs, int* __restrict__ adj) {
    __shared__ unsigned short sW[2*16384];   // 64 KB: W0 | W1 (fill blocks alias as cursor)
    const int t = threadIdx.x;

    if (blockIdx.x < G) {
        int* cur = reinterpret_cast<int*>(sW);
        int g = blockIdx.x;
        #pragma unroll
        for (int i = 0; i < 4; ++i) cur[i*512 + t] = offs[g*(N+1) + i*512 + t];
        __syncthreads();
        const int* srcp = ei + (size_t)g*2*E;
        const int* dstp = srcp + E;
        for (int e = t; e < E; e += 512) {
            int dst = dstp[e];
            int pos = atomicAdd(&cur[dst], 1);
            adj[(size_t)g*E + pos] = srcp[e];
        }
        return;
    }

    {
        const float4* s = reinterpret_cast<const float4*>(Wt);
        float4* d = reinterpret_cast<float4*>(sW);
        #pragma unroll
        for (int i = 0; i < 8; ++i) d[i*512 + t] = s[i*512 + t];
    }
    __syncthreads();

    const int lane = t & 63, w = t >> 6;
    const int wrow = (w & 3) << 6;     // 0,64,128,192
    const int wcol = (w >> 2) << 6;    // 0,64
    const size_t row0 = (size_t)swz(blockIdx.x - G, GN/256/8) * 256;
    const int l15 = lane & 15, l4 = lane >> 4;

    size_t rbase[4];
    const float* rowp[4];
    #pragma unroll
    for (int f2 = 0; f2 < 4; ++f2) {
        rbase[f2] = row0 + wrow + f2*16 + l15;
        rowp[f2] = tab + (size_t)fidx[rbase[f2]] * 128;
    }

    f32x4 acc0[4][4], acc1[4][4];
    #pragma unroll
    for (int i = 0; i < 4; ++i)
        #pragma unroll
        for (int j = 0; j < 4; ++j) {
            acc0[i][j] = (f32x4){0.f, 0.f, 0.f, 0.f};
            acc1[i][j] = (f32x4){0.f, 0.f, 0.f, 0.f};
        }

    #pragma unroll
    for (int kk = 0; kk < 4; ++kk) {
        bf16x8 xf[4];
        #pragma unroll
        for (int f2 = 0; f2 < 4; ++f2) {
            int col = (kk << 5) + (l4 << 3);
            float4 u = ld4(rowp[f2] + col);
            float4 v = ld4(rowp[f2] + col + 4);
            bf16x8 r;
            r[0] = (short)f2bf(u.x); r[1] = (short)f2bf(u.y);
            r[2] = (short)f2bf(u.z); r[3] = (short)f2bf(u.w);
            r[4] = (short)f2bf(v.x); r[5] = (short)f2bf(v.y);
            r[6] = (short)f2bf(v.z); r[7] = (short)f2bf(v.w);
            xf[f2] = r;
        }
        #pragma unroll
        for (int f = 0; f < 4; ++f) {
            int c = wcol + f*16 + l15;
            int off = c*128 + (((kk*4 + l4) ^ (c & 7)) << 3);
            bf16x8 wf0 = *reinterpret_cast<const bf16x8*>(&sW[off]);
            bf16x8 wf1 = *reinterpret_cast<const bf16x8*>(&sW[16384 + off]);
            #pragma unroll
            for (int f2 = 0; f2 < 4; ++f2) {
                acc0[f2][f] = __builtin_amdgcn_mfma_f32_16x16x32_bf16(wf0, xf[f2], acc0[f2][f], 0, 0, 0);
                acc1[f2][f] = __builtin_amdgcn_mfma_f32_16x16x32_bf16(wf1, xf[f2], acc1[f2][f], 0, 0, 0);
            }
        }
    }

    float dv[4];
    #pragma unroll
    for (int f2 = 0; f2 < 4; ++f2) dv[f2] = dinv[rbase[f2]];

    #pragma unroll
    for (int f = 0; f < 4; ++f) {
        int colb = wcol + f*16 + (l4 << 2);
        float4 bs = ld4(bres + colb);
        #pragma unroll
        for (int f2 = 0; f2 < 4; ++f2) {
            f32x4 v0 = acc0[f2][f];
            uint2 p0;
            p0.x = pack2(fmaxf(v0[0] + bs.x, 0.f), fmaxf(v0[1] + bs.y, 0.f));
            p0.y = pack2(fmaxf(v0[2] + bs.z, 0.f), fmaxf(v0[3] + bs.w, 0.f));
            *reinterpret_cast<uint2*>(X1 + (rbase[f2] << 7) + colb) = p0;
            f32x4 v1 = acc1[f2][f];
            float d = dv[f2];
            uint2 p1;
            p1.x = pack2(v1[0]*d, v1[1]*d);
            p1.y = pack2(v1[2]*d, v1[3]*d);
            *reinterpret_cast<uint2*>(Hb + (rbase[f2] << 7) + colb) = p1;
        }
    }
}

// ---------------- MFMA GEMM: 512 thr, 256-row tiles, XCD-swizzled ----------------
// MODE 1: C = (A@W) * dinv[row]
// MODE 2: colsum(relu((A+A2)@W + bias)) -> atomicAdd tgt  (no C write)
template<int MODE>
__global__ __launch_bounds__(512) void k_gemm(const unsigned short* __restrict__ A,
        const unsigned short* __restrict__ A2, const unsigned short* __restrict__ Wt,
        const float* __restrict__ bias, const float* __restrict__ dinv,
        unsigned short* __restrict__ C, float* __restrict__ tgt) {
    __shared__ unsigned short sW[16384];   // 32 KB, pre-swizzled
    const int t = threadIdx.x;
    {
        const float4* s = reinterpret_cast<const float4*>(Wt);
        float4* d = reinterpret_cast<float4*>(sW);
        #pragma unroll
        for (int i = 0; i < 4; ++i) d[i*512 + t] = s[i*512 + t];
    }
    __syncthreads();

    const int lane = t & 63, w = t >> 6;
    const int wrow = (w & 3) << 6;     // 0,64,128,192
    const int wcol = (w >> 2) << 6;    // 0,64
    const size_t row0 = (size_t)swz(blockIdx.x, GN/256/8) * 256;
    const int l15 = lane & 15, l4 = lane >> 4;

    size_t rbase[4];
    #pragma unroll
    for (int f2 = 0; f2 < 4; ++f2) rbase[f2] = row0 + wrow + f2*16 + l15;

    f32x4 acc[4][4];
    #pragma unroll
    for (int i = 0; i < 4; ++i)
        #pragma unroll
        for (int j = 0; j < 4; ++j) acc[i][j] = (f32x4){0.f, 0.f, 0.f, 0.f};

    #pragma unroll
    for (int kk = 0; kk < 4; ++kk) {
        bf16x8 xf[4];
        #pragma unroll
        for (int f2 = 0; f2 < 4; ++f2) {
            const unsigned short* ap = A + (rbase[f2] << 7) + (kk << 5) + (l4 << 3);
            if (MODE == 2) {
                bf16x8 x = *reinterpret_cast<const bf16x8*>(ap);
                bf16x8 y = *reinterpret_cast<const bf16x8*>(A2 + (rbase[f2] << 7) + (kk << 5) + (l4 << 3));
                bf16x8 r;
                #pragma unroll
                for (int j = 0; j < 8; ++j) r[j] = (short)f2bf(bfs(x[j]) + bfs(y[j]));
                xf[f2] = r;
            } else {
                xf[f2] = *reinterpret_cast<const bf16x8*>(ap);
            }
        }
        #pragma unroll
        for (int f = 0; f < 4; ++f) {
            int c = wcol + f*16 + l15;
            int off = c*128 + (((kk*4 + l4) ^ (c & 7)) << 3);
            bf16x8 wf = *reinterpret_cast<const bf16x8*>(&sW[off]);
            #pragma unroll
            for (int f2 = 0; f2 < 4; ++f2)
                acc[f2][f] = __builtin_amdgcn_mfma_f32_16x16x32_bf16(wf, xf[f2], acc[f2][f], 0, 0, 0);
        }
    }

    if (MODE == 2) {
        float cs[4][4];
        #pragma unroll
        for (int f = 0; f < 4; ++f) {
            int colb = wcol + f*16 + (l4 << 2);
            float4 bs = ld4(bias + colb);
            #pragma unroll
            for (int j = 0; j < 4; ++j) cs[f][j] = 0.f;
            #pragma unroll
            for (int f2 = 0; f2 < 4; ++f2) {
                cs[f][0] += fmaxf(acc[f2][f][0] + bs.x, 0.f);
                cs[f][1] += fmaxf(acc[f2][f][1] + bs.y, 0.f);
                cs[f][2] += fmaxf(acc[f2][f][2] + bs.z, 0.f);
                cs[f][3] += fmaxf(acc[f2][f][3] + bs.w, 0.f);
            }
        }
        #pragma unroll
        for (int d = 1; d < 16; d <<= 1)
            #pragma unroll
            for (int f = 0; f < 4; ++f)
                #pragma unroll
                for (int j = 0; j < 4; ++j)
                    cs[f][j] += __shfl_xor(cs[f][j], d);
        if (l15 == 0) {
            int g = (int)(row0 >> 11);
            #pragma unroll
            for (int f = 0; f < 4; ++f)
                #pragma unroll
                for (int j = 0; j < 4; ++j)
                    atomicAdd(&tgt[g*128 + wcol + f*16 + (l4 << 2) + j], cs[f][j]);
        }
        return;
    }

    float dv[4];
    #pragma unroll
    for (int f2 = 0; f2 < 4; ++f2) dv[f2] = dinv[rbase[f2]];
    #pragma unroll
    for (int f = 0; f < 4; ++f) {
        int colb = wcol + f*16 + (l4 << 2);
        #pragma unroll
        for (int f2 = 0; f2 < 4; ++f2) {
            f32x4 v = acc[f2][f];
            float d = dv[f2];
            uint2 p; p.x = pack2(v[0]*d, v[1]*d); p.y = pack2(v[2]*d, v[3]*d);
            *reinterpret_cast<uint2*>(C + (rbase[f2] << 7) + colb) = p;
        }
    }
}

// ---------------- aggregation: LDS slice (80B stride, b128 reads), degree-sorted nodes ----------------
__global__ __launch_bounds__(1024) void k_agg(const unsigned short* __restrict__ h,
        const int* __restrict__ adj, const int* __restrict__ offs,
        const int* __restrict__ perm,
        const float* __restrict__ dinv, const float* __restrict__ bias,
        unsigned short* __restrict__ out) {
    __shared__ unsigned short sIN[2048 * PADR];   // 160 KiB exactly
    const int t = threadIdx.x;
    const int g  = blockIdx.x >> 2;
    const int c0 = (blockIdx.x & 3) << 5;         // 0,32,64,96
    const unsigned short* hg = h + (((size_t)g << 11) << 7) + c0;

    // stage: 8 lanes per row, 8 B each
    {
        int r0 = t >> 3;     // 0..127
        int j  = t & 7;      // 8B chunk
        for (int i = 0; i < 16; ++i) {
            int r = r0 + (i << 7);
            uint2 v = *reinterpret_cast<const uint2*>(hg + ((size_t)r << 7) + j*4);
            *reinterpret_cast<uint2*>(&sIN[r*PADR + j*4]) = v;
        }
    }
    __syncthreads();

    const int* al = adj + (size_t)g*E;
    float bs[32];
    #pragma unroll
    for (int q = 0; q < 8; ++q) {
        float4 b4 = ld4(bias + c0 + q*4);
        bs[q*4] = b4.x; bs[q*4+1] = b4.y; bs[q*4+2] = b4.z; bs[q*4+3] = b4.w;
    }

    #pragma unroll
    for (int i = 0; i < 2; ++i) {
        int n = perm[(g << 11) + t + (i << 10)];   // degree-sorted -> uniform wave latency
        int st = offs[g*(N+1) + n];
        int en = offs[g*(N+1) + n + 1];
        float acc[32];
        {   // self-loop init from LDS (4 x b128)
            const unsigned short* rp = &sIN[n*PADR];
            #pragma unroll
            for (int k = 0; k < 4; ++k) {
                uint4 u = *reinterpret_cast<const uint4*>(rp + k*8);
                acc[k*8]   = bflo(u.x); acc[k*8+1] = bfhi(u.x);
                acc[k*8+2] = bflo(u.y); acc[k*8+3] = bfhi(u.y);
                acc[k*8+4] = bflo(u.z); acc[k*8+5] = bfhi(u.z);
                acc[k*8+6] = bflo(u.w); acc[k*8+7] = bfhi(u.w);
            }
        }
        int e = st;
        for (; e + 2 <= en; e += 2) {   // 2 edges in flight: 8 independent b128 reads
            int s0 = al[e], s1 = al[e+1];
            const unsigned short* rp0 = &sIN[s0*PADR];
            const unsigned short* rp1 = &sIN[s1*PADR];
            uint4 u0[4], u1[4];
            #pragma unroll
            for (int k = 0; k < 4; ++k) u0[k] = *reinterpret_cast<const uint4*>(rp0 + k*8);
            #pragma unroll
            for (int k = 0; k < 4; ++k) u1[k] = *reinterpret_cast<const uint4*>(rp1 + k*8);
            #pragma unroll
            for (int k = 0; k < 4; ++k) {
                acc[k*8]   += bflo(u0[k].x) + bflo(u1[k].x);
                acc[k*8+1] += bfhi(u0[k].x) + bfhi(u1[k].x);
                acc[k*8+2] += bflo(u0[k].y) + bflo(u1[k].y);
                acc[k*8+3] += bfhi(u0[k].y) + bfhi(u1[k].y);
                acc[k*8+4] += bflo(u0[k].z) + bflo(u1[k].z);
                acc[k*8+5] += bfhi(u0[k].z) + bfhi(u1[k].z);
                acc[k*8+6] += bflo(u0[k].w) + bflo(u1[k].w);
                acc[k*8+7] += bfhi(u0[k].w) + bfhi(u1[k].w);
            }
        }
        if (e < en) {
            const unsigned short* rp = &sIN[al[e]*PADR];
            #pragma unroll
            for (int k = 0; k < 4; ++k) {
                uint4 u = *reinterpret_cast<const uint4*>(rp + k*8);
                acc[k*8]   += bflo(u.x); acc[k*8+1] += bfhi(u.x);
                acc[k*8+2] += bflo(u.y); acc[k*8+3] += bfhi(u.y);
                acc[k*8+4] += bflo(u.z); acc[k*8+5] += bfhi(u.z);
                acc[k*8+6] += bflo(u.w); acc[k*8+7] += bfhi(u.w);
            }
        }
        float d = dinv[(g << 11) + n];
        unsigned short* op = out + (((size_t)(g << 11) + n) << 7) + c0;
        uint4 o0, o1;
        o0.x = pack2(fmaxf(acc[0]*d+bs[0],0.f),  fmaxf(acc[1]*d+bs[1],0.f));
        o0.y = pack2(fmaxf(acc[2]*d+bs[2],0.f),  fmaxf(acc[3]*d+bs[3],0.f));
        o0.z = pack2(fmaxf(acc[4]*d+bs[4],0.f),  fmaxf(acc[5]*d+bs[5],0.f));
        o0.w = pack2(fmaxf(acc[6]*d+bs[6],0.f),  fmaxf(acc[7]*d+bs[7],0.f));
        o1.x = pack2(fmaxf(acc[8]*d+bs[8],0.f),  fmaxf(acc[9]*d+bs[9],0.f));
        o1.y = pack2(fmaxf(acc[10]*d+bs[10],0.f),fmaxf(acc[11]*d+bs[11],0.f));
        o1.z = pack2(fmaxf(acc[12]*d+bs[12],0.f),fmaxf(acc[13]*d+bs[13],0.f));
        o1.w = pack2(fmaxf(acc[14]*d+bs[14],0.f),fmaxf(acc[15]*d+bs[15],0.f));
        *reinterpret_cast<uint4*>(op) = o0;
        *reinterpret_cast<uint4*>(op + 8) = o1;
        uint4 o2, o3;
        o2.x = pack2(fmaxf(acc[16]*d+bs[16],0.f),fmaxf(acc[17]*d+bs[17],0.f));
        o2.y = pack2(fmaxf(acc[18]*d+bs[18],0.f),fmaxf(acc[19]*d+bs[19],0.f));
        o2.z = pack2(fmaxf(acc[20]*d+bs[20],0.f),fmaxf(acc[21]*d+bs[21],0.f));
        o2.w = pack2(fmaxf(acc[22]*d+bs[22],0.f),fmaxf(acc[23]*d+bs[23],0.f));
        o3.x = pack2(fmaxf(acc[24]*d+bs[24],0.f),fmaxf(acc[25]*d+bs[25],0.f));
        o3.y = pack2(fmaxf(acc[26]*d+bs[26],0.f),fmaxf(acc[27]*d+bs[27],0.f));
        o3.z = pack2(fmaxf(acc[28]*d+bs[28],0.f),fmaxf(acc[29]*d+bs[29],0.f));
        o3.w = pack2(fmaxf(acc[30]*d+bs[30],0.f),fmaxf(acc[31]*d+bs[31],0.f));
        *reinterpret_cast<uint4*>(op + 16) = o2;
        *reinterpret_cast<uint4*>(op + 24) = o3;
    }
}

// ---------------- logits + log_softmax: one wave per graph ----------------
__global__ __launch_bounds__(64) void k_final(const float* __restrict__ tgt,
        const float* __restrict__ lw, const float* __restrict__ lb, float* __restrict__ outp) {
    int g = blockIdx.x, lane = threadIdx.x;
    float l0 = 0.f, l1 = 0.f;
    #pragma unroll
    for (int c = lane; c < 128; c += 64) {
        float v = tgt[g*128 + c] * (1.0f/2048.0f);
        l0 += v * lw[c*2];
        l1 += v * lw[c*2 + 1];
    }
    #pragma unroll
    for (int d = 32; d; d >>= 1) { l0 += __shfl_xor(l0, d); l1 += __shfl_xor(l1, d); }
    if (lane == 0) {
        l0 += lb[0]; l1 += lb[1];
        float m = fmaxf(l0, l1);
        float lse = m + logf(expf(l0 - m) + expf(l1 - m));
        outp[g*2]         = l0 - lse;
        outp[g*2 + 1]     = l1 - lse;
        outp[G*2 + g*2]     = l0;
        outp[G*2 + g*2 + 1] = l1;
    }
}

extern "C" void kernel_launch(void* const* d_in, const int* in_sizes, int n_in,
                              void* d_out, int out_size, void* d_ws, size_t ws_size,
                              hipStream_t stream) {
    const float* all_features = (const float*)d_in[0];
    const int*   fidx = (const int*)d_in[1];
    const int*   ei   = (const int*)d_in[2];
    // d_in[3] = action (always 2 -> 3 GCN layers)
    const float* wres = (const float*)d_in[4];
    const float* bres = (const float*)d_in[5];
    const float* gw   = (const float*)d_in[6];
    const float* gb   = (const float*)d_in[7];
    const float* wfc  = (const float*)d_in[8];
    const float* bfc  = (const float*)d_in[9];
    const float* lw   = (const float*)d_in[10];
    const float* lb   = (const float*)d_in[11];
    float* out = (float*)d_out;

    char* ws = (char*)d_ws;
    size_t o = 0;
    auto alloc = [&](size_t bytes) { char* p = ws + o; o += (bytes + 255) & ~(size_t)255; return p; };
    unsigned short* X  = (unsigned short*)alloc((size_t)GN*128*2);   // agg output
    unsigned short* Hb = (unsigned short*)alloc((size_t)GN*128*2);   // h'
    unsigned short* X1 = (unsigned short*)alloc((size_t)GN*128*2);   // residual
    unsigned short* Wt = (unsigned short*)alloc((size_t)5*16384*2);
    int*   adj  = (int*)alloc((size_t)G*E*4);
    int*   offs = (int*)alloc((size_t)G*(N+1)*4);
    int*   perm = (int*)alloc((size_t)GN*4);
    float* dinv = (float*)alloc((size_t)GN*4);
    float* tgt  = (float*)alloc((size_t)G*128*4);

    // CSR count/scan + degree-sort + weight prep + tgt zero (one launch)
    k_init<<<G + 41, 1024, 0, stream>>>(ei, offs, dinv, perm, wres, gw, wfc, Wt, tgt);

    // twin gather-GEMM (blocks 64..575) with CSR fill overlapped (blocks 0..63)
    k_gemm_g2<<<G + GN/256, 512, 0, stream>>>(fidx, all_features, Wt, bres, dinv, X1, Hb,
                                              ei, offs, adj);

    // layer 0 aggregation, then layers 1..2
    k_agg<<<G*4, 1024, 0, stream>>>(Hb, adj, offs, perm, dinv, gb, X);
    for (int l = 1; l < 3; ++l) {
        k_gemm<1><<<GN/256, 512, 0, stream>>>(X, nullptr, Wt + (size_t)(1+l)*16384, nullptr, dinv, Hb, nullptr);
        k_agg<<<G*4, 1024, 0, stream>>>(Hb, adj, offs, perm, dinv, gb + (size_t)l*128, X);
    }

    // fc1 + mean fused: atomicAdd col-sums of relu((X+X1)@Wfc+bfc) into tgt
    k_gemm<2><<<GN/256, 512, 0, stream>>>(X, X1, Wt + (size_t)4*16384, bfc, nullptr, nullptr, tgt);

    k_final<<<G, 64, 0, stream>>>(tgt, lw, lb, out);
}